// Round 5
// baseline (768.855 us; speedup 1.0000x reference)
//
#include <hip/hip_runtime.h>

typedef unsigned int u32;
typedef unsigned short u16;
typedef _Float16 half_t;
typedef half_t h2   __attribute__((ext_vector_type(2)));
typedef half_t f16x8 __attribute__((ext_vector_type(8)));
typedef float  f32x4 __attribute__((ext_vector_type(4)));

#define NPTS 1048576

// workspace dword layout (f16 feature-pair tables, built by ga_prep from fp32)
#define WS_LINE_DW   0        // 3*511*2*32 = 98112 dw: [line][i0][tap][fpair]
#define WS_VOL_DW    98112    // 125*32     =  4000 dw: [z*25+y*5+x][fpair]
#define WS_PLANE_DW  102112   // 3*400*32   = 38400 dw: [plane][row][swizzled chunk][fpair]
#define WS_TOTAL_DW  140512
#define WS_TOTAL_BYTES (WS_TOTAL_DW * 4)

// LDS layout (dwords): planes xy,yz at 0 (25600 dw), volume at 25600 (125 rows x 36 dw)
#define LDS_VOL_DW   25600
#define LDS_TOTAL_DW 30100        // 120,400 B -> 1 block/CU
#define VOLB         (LDS_VOL_DW*4)

__device__ __forceinline__ u32 pkh(float a, float b) {
    union { h2 h; u32 u; } r;
    r.h = (h2){(half_t)a, (half_t)b};
    return r.u;
}
__device__ __forceinline__ h2 bc(float w) {
    half_t h = (half_t)w;
    return (h2){h, h};
}

// ---------------------------------------------------------------------------
// Prep: fp32 inputs -> f16 feature-pair tables in d_ws. (unchanged)
// ---------------------------------------------------------------------------
__global__ __launch_bounds__(256) void ga_prep(
    const float* __restrict__ lx, const float* __restrict__ ly, const float* __restrict__ lz,
    const float* __restrict__ pxy, const float* __restrict__ pyz, const float* __restrict__ pzx,
    const float* __restrict__ vol, u32* __restrict__ ws)
{
    const int stride = gridDim.x * blockDim.x;
    for (int t = blockIdx.x * blockDim.x + threadIdx.x; t < WS_TOTAL_DW; t += stride) {
        if (t < WS_VOL_DW) {
            const int l  = t / 32704;           // 511*64
            const int r  = t - l * 32704;
            const int i0 = r >> 6;              // 0..510
            const int w  = r & 63;
            const int tap = w >> 5;
            const int fp  = w & 31;
            const float* L = (l == 0) ? lx : (l == 1) ? ly : lz;
            ws[t] = pkh(L[(2*fp)*512 + i0 + tap], L[(2*fp+1)*512 + i0 + tap]);
        } else if (t < WS_PLANE_DW) {
            const int r = t - WS_VOL_DW;
            const int vox = r >> 5;
            const int fp  = r & 31;
            ws[t] = pkh(vol[(2*fp)*125 + vox], vol[(2*fp+1)*125 + vox]);
        } else {
            const int r  = t - WS_PLANE_DW;
            const int pp = r / 12800;
            const int rr = r - pp * 12800;
            const int row = rr >> 5;            // 0..399 (= y*20+x)
            const int c   = rr & 31;            // fpair index
            const int chunk = c >> 2;
            const int ci    = c & 3;
            const int pos = ((chunk ^ (row & 7)) << 2) + ci;  // XOR swizzle
            const float* P = (pp == 0) ? pxy : (pp == 1) ? pyz : pzx;
            const int f = c * 2;
            ws[WS_PLANE_DW + pp*12800 + (row << 5) + pos] =
                pkh(P[f*400 + row], P[(f+1)*400 + row]);
        }
    }
}

// ---------------------------------------------------------------------------
// Main: lane = (point p = lane&15, feature group fg = lane>>4).
// 2-way unrolled point loop: two independent groups per iteration for ILP.
// LDS: planes xy,yz + padded volume. Plane zx + lines from L2.
// __launch_bounds__(1024,3): VGPR cap ~168 so the doubled live set fits.
// ---------------------------------------------------------------------------
__global__ __launch_bounds__(1024, 3) void ga_main(
    const float* __restrict__ coords,
    const float* __restrict__ w1,
    const float* __restrict__ b1,
    const float* __restrict__ w2,
    const float* __restrict__ b2,
    const u32* __restrict__ ws,
    float* __restrict__ out)
{
    __shared__ u32 sP[LDS_TOTAL_DW];   // 120,400 B
    const int tid = threadIdx.x;
    {
        const uint4* src = (const uint4*)(ws + WS_PLANE_DW);
        uint4* dst = (uint4*)sP;
        #pragma unroll
        for (int i = 0; i < 7; ++i) {
            int idx = tid + i * 1024;
            if (idx < 6400) dst[idx] = src[idx];
        }
        if (tid < 1000) {
            const int vox = tid >> 3, ch = tid & 7;
            ((uint4*)(sP + LDS_VOL_DW))[vox*9 + ch] = ((const uint4*)(ws + WS_VOL_DW))[tid];
        }
    }
    __syncthreads();

    const int lane = tid & 63;
    const int wave = tid >> 6;       // 0..15
    const int p    = lane & 15;
    const int fg   = lane >> 4;      // 0..3
    const int wgbase = blockIdx.x << 12;   // 4096 points per workgroup

    // w1 B-fragments (f16)
    f16x8 wfrag[4][2];
    #pragma unroll
    for (int t = 0; t < 4; ++t) {
        #pragma unroll
        for (int h = 0; h < 2; ++h) {
            const float* src = w1 + ((16*t + p)*64 + h*32 + fg*8);
            f16x8 w;
            #pragma unroll
            for (int e = 0; e < 8; ++e) w[e] = (half_t)src[e];
            wfrag[t][h] = w;
        }
    }
    float b1v[4], w2v[4];
    #pragma unroll
    for (int t = 0; t < 4; ++t) { b1v[t] = b1[16*t + p]; w2v[t] = w2[16*t + p]; }
    const float b2v = b2[0];

    const char* wsb = (const char*)ws;
    const char* spb = (const char*)sP;

    // coords prefetch for the first pair of groups
    float cx[2], cy[2], cz[2];
    #pragma unroll
    for (int u = 0; u < 2; ++u) {
        const int pt0 = wgbase + ((wave + u*16) << 4) + p;
        cx[u] = coords[3*pt0 + 0];
        cy[u] = coords[3*pt0 + 1];
        cz[u] = coords[3*pt0 + 2];
    }

    for (int g = wave; g < 256; g += 32) {
        // prefetch next pair's coords
        float nx[2], ny[2], nz[2];
        #pragma unroll
        for (int u = 0; u < 2; ++u) {
            int gn = g + 32 + u*16;
            if (gn >= 256) gn = g + u*16;
            const int ptn = wgbase + (gn << 4) + p;
            nx[u] = coords[3*ptn + 0];
            ny[u] = coords[3*ptn + 1];
            nz[u] = coords[3*ptn + 2];
        }

        // ---- index/weight math for both groups (independent streams) ----
        int laddr[2][3], paddr[2][3][4], vb[2];
        h2 wlm[2][3], wlw[2][3], wqb[2][3][4], wvb[2][8];
        #pragma unroll
        for (int u = 0; u < 2; ++u) {
            int lidx[3], pidx[3], vidx[3];
            float lww[3], lwmf[3], pww[3], pwm[3], vww[3], vwm[3];
            const float uu[3] = { (cx[u]+1.f)*0.5f, (cy[u]+1.f)*0.5f, (cz[u]+1.f)*0.5f };
            #pragma unroll
            for (int c = 0; c < 3; ++c) {
                float pos = fminf(fmaxf(uu[c]*511.f, 0.f), 511.f);
                float i0 = fminf(floorf(pos), 510.f);
                lidx[c] = (int)i0; lww[c] = pos - i0; lwmf[c] = 1.f - lww[c];
                float pq = fminf(fmaxf(uu[c]*19.f, 0.f), 19.f);
                float pi0 = fminf(floorf(pq), 18.f);
                pidx[c] = (int)pi0; pww[c] = pq - pi0; pwm[c] = 1.f - pww[c];
                float vq = fminf(fmaxf(uu[c]*4.f, 0.f), 4.f);
                float vi0 = fminf(floorf(vq), 3.f);
                vidx[c] = (int)vi0; vww[c] = vq - vi0; vwm[c] = 1.f - vww[c];
            }
            #pragma unroll
            for (int c = 0; c < 3; ++c) {
                laddr[u][c] = (c*511 + lidx[c])*256 + fg*16;
                wlm[u][c] = bc(lwmf[c]); wlw[u][c] = bc(lww[c]);
            }
            #pragma unroll
            for (int pp = 0; pp < 3; ++pp) {
                const int a = (pp==0)?0:(pp==1)?1:2;    // gx axis (col)
                const int b = (pp==0)?1:(pp==1)?2:0;    // gy axis (row)
                wqb[u][pp][0] = bc(pwm[b]*pwm[a]); wqb[u][pp][1] = bc(pwm[b]*pww[a]);
                wqb[u][pp][2] = bc(pww[b]*pwm[a]); wqb[u][pp][3] = bc(pww[b]*pww[a]);
                const int r00 = pidx[b]*20 + pidx[a];
                const int base = (pp == 2) ? (WS_PLANE_DW*4 + 2*51200) : pp*51200;
                const int roff[4] = {0, 1, 20, 21};
                #pragma unroll
                for (int k = 0; k < 4; ++k) {
                    const int r = r00 + roff[k];
                    paddr[u][pp][k] = base + r*128 + ((fg ^ (r & 7)) << 4);
                }
            }
            const int vox00 = (vidx[2]*5 + vidx[1])*5 + vidx[0];
            vb[u] = VOLB + vox00*144 + fg*16;
            #pragma unroll
            for (int dz = 0; dz < 2; ++dz)
                #pragma unroll
                for (int dy = 0; dy < 2; ++dy)
                    #pragma unroll
                    for (int dx = 0; dx < 2; ++dx)
                        wvb[u][dz*4+dy*2+dx] =
                            bc((dz?vww[2]:vwm[2])*(dy?vww[1]:vwm[1])*(dx?vww[0]:vwm[0]));
        }

        union UH { uint4 v; h2 h[4]; };
        h2 comb[2][2][4];
        // ---- per (group, cc): globals first, volume from LDS, math ----
        #pragma unroll
        for (int u = 0; u < 2; ++u) {
            #pragma unroll
            for (int cc = 0; cc < 2; ++cc) {
                const int co = cc * 64;
                // globals: lines (6) + plane-zx (4)
                UH X0, X1, Y0, Y1, Z0, Z1;
                X0.v = *(const uint4*)(wsb + laddr[u][0] + co);
                X1.v = *(const uint4*)(wsb + laddr[u][0] + co + 128);
                Y0.v = *(const uint4*)(wsb + laddr[u][1] + co);
                Y1.v = *(const uint4*)(wsb + laddr[u][1] + co + 128);
                Z0.v = *(const uint4*)(wsb + laddr[u][2] + co);
                Z1.v = *(const uint4*)(wsb + laddr[u][2] + co + 128);
                UH q0, q1, q2, q3;
                q0.v = *(const uint4*)(wsb + (paddr[u][2][0] ^ co));
                q1.v = *(const uint4*)(wsb + (paddr[u][2][1] ^ co));
                q2.v = *(const uint4*)(wsb + (paddr[u][2][2] ^ co));
                q3.v = *(const uint4*)(wsb + (paddr[u][2][3] ^ co));
                // volume from LDS while globals fly
                UH V[8];
                #pragma unroll
                for (int dz = 0; dz < 2; ++dz)
                    #pragma unroll
                    for (int dy = 0; dy < 2; ++dy)
                        #pragma unroll
                        for (int dx = 0; dx < 2; ++dx)
                            V[dz*4+dy*2+dx].v =
                                *(const uint4*)(spb + vb[u] + (dz*25+dy*5+dx)*144 + co);
                #pragma unroll
                for (int j = 0; j < 4; ++j) {
                    h2 s = V[0].h[j]*wvb[u][0] + V[1].h[j]*wvb[u][1]
                         + V[2].h[j]*wvb[u][2] + V[3].h[j]*wvb[u][3];
                    s += V[4].h[j]*wvb[u][4] + V[5].h[j]*wvb[u][5]
                       + V[6].h[j]*wvb[u][6] + V[7].h[j]*wvb[u][7];
                    comb[u][cc][j] = s;
                }
                // planes xy,yz from LDS
                UH r0[2], r1[2], r2[2], r3[2];
                #pragma unroll
                for (int pp = 0; pp < 2; ++pp) {
                    r0[pp].v = *(const uint4*)(spb + (paddr[u][pp][0] ^ co));
                    r1[pp].v = *(const uint4*)(spb + (paddr[u][pp][1] ^ co));
                    r2[pp].v = *(const uint4*)(spb + (paddr[u][pp][2] ^ co));
                    r3[pp].v = *(const uint4*)(spb + (paddr[u][pp][3] ^ co));
                }
                // line lerps (needs globals)
                h2 fx[4], fy[4], fz[4];
                #pragma unroll
                for (int j = 0; j < 4; ++j) {
                    fx[j] = X0.h[j]*wlm[u][0] + X1.h[j]*wlw[u][0];
                    fy[j] = Y0.h[j]*wlm[u][1] + Y1.h[j]*wlw[u][1];
                    fz[j] = Z0.h[j]*wlm[u][2] + Z1.h[j]*wlw[u][2];
                }
                #pragma unroll
                for (int j = 0; j < 4; ++j) comb[u][cc][j] += fx[j]*fy[j]*fz[j];
                #pragma unroll
                for (int pp = 0; pp < 2; ++pp) {
                    #pragma unroll
                    for (int j = 0; j < 4; ++j) {
                        h2 pa = r0[pp].h[j]*wqb[u][pp][0] + r1[pp].h[j]*wqb[u][pp][1]
                              + r2[pp].h[j]*wqb[u][pp][2] + r3[pp].h[j]*wqb[u][pp][3];
                        const h2 lf = (pp==0) ? fz[j] : fx[j];
                        comb[u][cc][j] += pa * lf;
                    }
                }
                #pragma unroll
                for (int j = 0; j < 4; ++j) {
                    h2 pa = q0.h[j]*wqb[u][2][0] + q1.h[j]*wqb[u][2][1]
                          + q2.h[j]*wqb[u][2][2] + q3.h[j]*wqb[u][2][3];
                    comb[u][cc][j] += pa * fy[j];
                }
            }
        }

        // ---- MLP + reduce + store, both groups (independent) ----
        #pragma unroll
        for (int u = 0; u < 2; ++u) {
            union AF { f16x8 v; h2 h[4]; } A0, A1;
            #pragma unroll
            for (int j = 0; j < 4; ++j) { A0.h[j] = comb[u][0][j]; A1.h[j] = comb[u][1][j]; }
            f32x4 acc0 = {0.f,0.f,0.f,0.f};
            f32x4 acc1 = {0.f,0.f,0.f,0.f};
            f32x4 acc2 = {0.f,0.f,0.f,0.f};
            f32x4 acc3 = {0.f,0.f,0.f,0.f};
            acc0 = __builtin_amdgcn_mfma_f32_16x16x32_f16(A0.v, wfrag[0][0], acc0, 0, 0, 0);
            acc0 = __builtin_amdgcn_mfma_f32_16x16x32_f16(A1.v, wfrag[0][1], acc0, 0, 0, 0);
            acc1 = __builtin_amdgcn_mfma_f32_16x16x32_f16(A0.v, wfrag[1][0], acc1, 0, 0, 0);
            acc1 = __builtin_amdgcn_mfma_f32_16x16x32_f16(A1.v, wfrag[1][1], acc1, 0, 0, 0);
            acc2 = __builtin_amdgcn_mfma_f32_16x16x32_f16(A0.v, wfrag[2][0], acc2, 0, 0, 0);
            acc2 = __builtin_amdgcn_mfma_f32_16x16x32_f16(A1.v, wfrag[2][1], acc2, 0, 0, 0);
            acc3 = __builtin_amdgcn_mfma_f32_16x16x32_f16(A0.v, wfrag[3][0], acc3, 0, 0, 0);
            acc3 = __builtin_amdgcn_mfma_f32_16x16x32_f16(A1.v, wfrag[3][1], acc3, 0, 0, 0);
            float sr[4];
            #pragma unroll
            for (int r = 0; r < 4; ++r) {
                float s = fmaxf(acc0[r] + b1v[0], 0.f) * w2v[0];
                s = fmaf(fmaxf(acc1[r] + b1v[1], 0.f), w2v[1], s);
                s = fmaf(fmaxf(acc2[r] + b1v[2], 0.f), w2v[2], s);
                s = fmaf(fmaxf(acc3[r] + b1v[3], 0.f), w2v[3], s);
                sr[r] = s;
            }
            #pragma unroll
            for (int m = 1; m <= 8; m <<= 1) {
                #pragma unroll
                for (int r = 0; r < 4; ++r) sr[r] += __shfl_xor(sr[r], m, 64);
            }
            if (p == 0) {
                const int pbase = wgbase + ((g + u*16) << 4);
                float4 o;
                o.x = sr[0] + b2v;
                o.y = sr[1] + b2v;
                o.z = sr[2] + b2v;
                o.w = sr[3] + b2v;
                *(float4*)(out + pbase + (fg << 2)) = o;
            }
        }
        #pragma unroll
        for (int u = 0; u < 2; ++u) { cx[u] = nx[u]; cy[u] = ny[u]; cz[u] = nz[u]; }
    }
}

// ---------------------------------------------------------------------------
// Fallback (only if ws_size is too small): slow but correct, thread-per-point.
// ---------------------------------------------------------------------------
__global__ __launch_bounds__(256) void ga_naive(
    const float* __restrict__ coords,
    const float* __restrict__ lx, const float* __restrict__ ly, const float* __restrict__ lz,
    const float* __restrict__ pxy, const float* __restrict__ pyz, const float* __restrict__ pzx,
    const float* __restrict__ vol,
    const float* __restrict__ w1, const float* __restrict__ b1,
    const float* __restrict__ w2, const float* __restrict__ b2,
    float* __restrict__ out)
{
    const int n = blockIdx.x * blockDim.x + threadIdx.x;
    if (n >= NPTS) return;
    int lidx[3], pidx[3], vidx[3];
    float lww[3], lwm[3], pww[3], pwm[3], vww[3], vwm[3];
    for (int c = 0; c < 3; ++c) {
        const float cv = coords[3*n + c];
        const float u = (cv + 1.f)*0.5f;
        float pos = fminf(fmaxf(u*511.f, 0.f), 511.f);
        float i0 = fminf(floorf(pos), 510.f);
        lidx[c] = (int)i0; lww[c] = pos - i0; lwm[c] = 1.f - lww[c];
        float pq = fminf(fmaxf(u*19.f, 0.f), 19.f);
        float pi0 = fminf(floorf(pq), 18.f);
        pidx[c] = (int)pi0; pww[c] = pq - pi0; pwm[c] = 1.f - pww[c];
        float vq = fminf(fmaxf(u*4.f, 0.f), 4.f);
        float vi0 = fminf(floorf(vq), 3.f);
        vidx[c] = (int)vi0; vww[c] = vq - vi0; vwm[c] = 1.f - vww[c];
    }
    float comb[64];
    for (int f = 0; f < 64; ++f) {
        const float fxv = lwm[0]*lx[f*512+lidx[0]] + lww[0]*lx[f*512+lidx[0]+1];
        const float fyv = lwm[1]*ly[f*512+lidx[1]] + lww[1]*ly[f*512+lidx[1]+1];
        const float fzv = lwm[2]*lz[f*512+lidx[2]] + lww[2]*lz[f*512+lidx[2]+1];
        const int bxy = f*400 + pidx[1]*20 + pidx[0];
        const float pxyv = pwm[1]*pwm[0]*pxy[bxy]    + pwm[1]*pww[0]*pxy[bxy+1]
                         + pww[1]*pwm[0]*pxy[bxy+20] + pww[1]*pww[0]*pxy[bxy+21];
        const int byz = f*400 + pidx[2]*20 + pidx[1];
        const float pyzv = pwm[2]*pwm[1]*pyz[byz]    + pwm[2]*pww[1]*pyz[byz+1]
                         + pww[2]*pwm[1]*pyz[byz+20] + pww[2]*pww[1]*pyz[byz+21];
        const int bzx = f*400 + pidx[0]*20 + pidx[2];
        const float pzxv = pwm[0]*pwm[2]*pzx[bzx]    + pwm[0]*pww[2]*pzx[bzx+1]
                         + pww[0]*pwm[2]*pzx[bzx+20] + pww[0]*pww[2]*pzx[bzx+21];
        const int bv = f*125 + (vidx[2]*5 + vidx[1])*5 + vidx[0];
        float vv = 0.f;
        for (int dz = 0; dz < 2; ++dz)
            for (int dy = 0; dy < 2; ++dy)
                for (int dx = 0; dx < 2; ++dx) {
                    const float w = (dz ? vww[2] : vwm[2]) * (dy ? vww[1] : vwm[1]) * (dx ? vww[0] : vwm[0]);
                    vv += w * vol[bv + dz*25 + dy*5 + dx];
                }
        comb[f] = fxv*fyv*fzv + pxyv*fzv + pyzv*fxv + pzxv*fyv + vv;
    }
    float o = b2[0];
    for (int gg = 0; gg < 64; ++gg) {
        float h = b1[gg];
        for (int f = 0; f < 64; ++f) h = fmaf(comb[f], w1[gg*64 + f], h);
        o = fmaf(fmaxf(h, 0.f), w2[gg], o);
    }
    out[n] = o;
}

extern "C" void kernel_launch(void* const* d_in, const int* in_sizes, int n_in,
                              void* d_out, int out_size, void* d_ws, size_t ws_size,
                              hipStream_t stream)
{
    const float* coords = (const float*)d_in[0];
    const float* lx  = (const float*)d_in[1];
    const float* ly  = (const float*)d_in[2];
    const float* lz  = (const float*)d_in[3];
    const float* pxy = (const float*)d_in[4];
    const float* pyz = (const float*)d_in[5];
    const float* pzx = (const float*)d_in[6];
    const float* vol = (const float*)d_in[7];
    const float* w1  = (const float*)d_in[8];
    const float* b1  = (const float*)d_in[9];
    const float* w2  = (const float*)d_in[10];
    const float* b2  = (const float*)d_in[11];
    float* out = (float*)d_out;
    if (ws_size >= (size_t)WS_TOTAL_BYTES) {
        u32* ws = (u32*)d_ws;
        ga_prep<<<dim3(550), dim3(256), 0, stream>>>(lx, ly, lz, pxy, pyz, pzx, vol, ws);
        ga_main<<<dim3(256), dim3(1024), 0, stream>>>(coords, w1, b1, w2, b2, ws, out);
    } else {
        ga_naive<<<dim3(4096), dim3(256), 0, stream>>>(coords, lx, ly, lz, pxy, pyz, pzx, vol,
                                                       w1, b1, w2, b2, out);
    }
}

// Round 7
// 218.588 us; speedup vs baseline: 3.5174x; 3.5174x over previous
//
#include <hip/hip_runtime.h>

typedef unsigned int u32;
typedef unsigned short u16;
typedef _Float16 half_t;
typedef half_t h2   __attribute__((ext_vector_type(2)));
typedef half_t f16x8 __attribute__((ext_vector_type(8)));
typedef float  f32x4 __attribute__((ext_vector_type(4)));
typedef float  f32x2 __attribute__((ext_vector_type(2)));
typedef __fp16 fp16v2 __attribute__((ext_vector_type(2)));

#define NPTS 1048576

#if defined(__has_builtin)
#if __has_builtin(__builtin_amdgcn_cvt_pk_f32_fp8) && __has_builtin(__builtin_amdgcn_cvt_pk_fp8_f32) && __has_builtin(__builtin_amdgcn_cvt_pkrtz)
#define HAS_FP8 1
#endif
#endif
#ifndef HAS_FP8
#define HAS_FP8 0
#endif

// workspace dword layout (built by ga_prep from fp32 inputs)
#define WS_LINE_DW   0        // 3*511*2*32 = 98112 dw: [line][i0][tap][fpair] f16 pairs
#define WS_VOL_DW    98112    // 125*32     =  4000 dw: [z*25+y*5+x][fpair] f16 pairs
#define WS_PLANE_DW  102112   // 3*400*32   = 38400 dw: [plane][row][swizzled chunk][fpair] f16
#define WS_PZX8_DW   140512   // 400*18     =  7200 dw: [row][fp8 features x64 + 8B pad]
#define WS_TOTAL_DW  147712
#define WS_TOTAL_BYTES (WS_TOTAL_DW * 4)

// LDS layout (dwords): planes xy,yz at 0 (25600 dw); volume at 25600 (125 rows x 36 dw);
// pzx-fp8 at 30100 (400 rows x 18 dw). Total 37300 dw = 149,200 B -> 1 block/CU.
#define LDS_VOL_DW   25600
#define LDS_PZ8_DW   30100
#define LDS_TOTAL_DW 37300
#define VOLB         (LDS_VOL_DW*4)    // 102400
#define PZ8B         (LDS_PZ8_DW*4)    // 120400

__device__ __forceinline__ u32 pkh(float a, float b) {
    union { h2 h; u32 u; } r;
    r.h = (h2){(half_t)a, (half_t)b};
    return r.u;
}
__device__ __forceinline__ h2 bc(float w) {
    half_t h = (half_t)w;
    return (h2){h, h};
}
__device__ __forceinline__ h2 pkrtz(float a, float b) {
    union { fp16v2 f; h2 h; } r;
    r.f = __builtin_amdgcn_cvt_pkrtz(a, b);
    return r.h;
}

// ---------------------------------------------------------------------------
// Prep: fp32 inputs -> f16 pair tables + fp8 pzx table in d_ws.
// ---------------------------------------------------------------------------
__global__ __launch_bounds__(256) void ga_prep(
    const float* __restrict__ lx, const float* __restrict__ ly, const float* __restrict__ lz,
    const float* __restrict__ pxy, const float* __restrict__ pyz, const float* __restrict__ pzx,
    const float* __restrict__ vol, u32* __restrict__ ws)
{
    const int stride = gridDim.x * blockDim.x;
    for (int t = blockIdx.x * blockDim.x + threadIdx.x; t < WS_TOTAL_DW; t += stride) {
        if (t < WS_VOL_DW) {
            const int l  = t / 32704;           // 511*64
            const int r  = t - l * 32704;
            const int i0 = r >> 6;              // 0..510
            const int w  = r & 63;
            const int tap = w >> 5;
            const int fp  = w & 31;
            const float* L = (l == 0) ? lx : (l == 1) ? ly : lz;
            ws[t] = pkh(L[(2*fp)*512 + i0 + tap], L[(2*fp+1)*512 + i0 + tap]);
        } else if (t < WS_PLANE_DW) {
            const int r = t - WS_VOL_DW;
            const int vox = r >> 5;
            const int fp  = r & 31;
            ws[t] = pkh(vol[(2*fp)*125 + vox], vol[(2*fp+1)*125 + vox]);
        } else if (t < WS_PZX8_DW) {
            const int r  = t - WS_PLANE_DW;
            const int pp = r / 12800;
            const int rr = r - pp * 12800;
            const int row = rr >> 5;            // 0..399 (= y*20+x)
            const int c   = rr & 31;            // fpair index
            const int chunk = c >> 2;
            const int ci    = c & 3;
            const int pos = ((chunk ^ (row & 7)) << 2) + ci;  // XOR swizzle
            const float* P = (pp == 0) ? pxy : (pp == 1) ? pyz : pzx;
            const int f = c * 2;
            ws[WS_PLANE_DW + pp*12800 + (row << 5) + pos] =
                pkh(P[f*400 + row], P[(f+1)*400 + row]);
        } else {
            const int t2 = t - WS_PZX8_DW;
            const int row = t2 / 18;
            const int d   = t2 - row * 18;
            u32 v = 0;
#if HAS_FP8
            if (d < 16) {
                const int f0 = d * 4;
                int dw = 0;
                dw = __builtin_amdgcn_cvt_pk_fp8_f32(pzx[(f0+0)*400+row], pzx[(f0+1)*400+row], dw, false);
                dw = __builtin_amdgcn_cvt_pk_fp8_f32(pzx[(f0+2)*400+row], pzx[(f0+3)*400+row], dw, true);
                v = (u32)dw;
            }
#endif
            ws[t] = v;
        }
    }
}

// ---------------------------------------------------------------------------
// Main: lane = (point p = lane&15, feature group fg = lane>>4).
// LDS: planes xy,yz (102.4 KB f16) + padded volume (18 KB f16) + pzx (28.8 KB fp8).
// Only the 3 line tables come from L2 -> 12.25 divergent lines/point (was 20).
// Structure identical to round-4 (which compiled clean at VGPR 64, no scratch).
// ---------------------------------------------------------------------------
__global__ __launch_bounds__(1024, 4) void ga_main(
    const float* __restrict__ coords,
    const float* __restrict__ w1,
    const float* __restrict__ b1,
    const float* __restrict__ w2,
    const float* __restrict__ b2,
    const u32* __restrict__ ws,
    float* __restrict__ out)
{
    __shared__ u32 sP[LDS_TOTAL_DW];   // 149,200 B
    const int tid = threadIdx.x;
    {
        const uint4* src = (const uint4*)(ws + WS_PLANE_DW);
        uint4* dst = (uint4*)sP;
        #pragma unroll
        for (int i = 0; i < 7; ++i) {
            int idx = tid + i * 1024;
            if (idx < 6400) dst[idx] = src[idx];
        }
        if (tid < 1000) {
            const int vox = tid >> 3, ch = tid & 7;
            ((uint4*)(sP + LDS_VOL_DW))[vox*9 + ch] = ((const uint4*)(ws + WS_VOL_DW))[tid];
        }
#if HAS_FP8
        #pragma unroll
        for (int i = 0; i < 2; ++i) {
            int idx = tid + i * 1024;
            if (idx < 1800)
                ((uint4*)(sP + LDS_PZ8_DW))[idx] = ((const uint4*)(ws + WS_PZX8_DW))[idx];
        }
#endif
    }
    __syncthreads();

    const int lane = tid & 63;
    const int wave = tid >> 6;       // 0..15
    const int p    = lane & 15;
    const int fg   = lane >> 4;      // 0..3
    const int wgbase = blockIdx.x << 12;   // 4096 points per workgroup

    // w1 B-fragments (f16)
    f16x8 wfrag[4][2];
    #pragma unroll
    for (int t = 0; t < 4; ++t) {
        #pragma unroll
        for (int h = 0; h < 2; ++h) {
            const float* src = w1 + ((16*t + p)*64 + h*32 + fg*8);
            f16x8 w;
            #pragma unroll
            for (int e = 0; e < 8; ++e) w[e] = (half_t)src[e];
            wfrag[t][h] = w;
        }
    }
    float b1v[4], w2v[4];
    #pragma unroll
    for (int t = 0; t < 4; ++t) { b1v[t] = b1[16*t + p]; w2v[t] = w2[16*t + p]; }
    const float b2v = b2[0];

    const char* wsb = (const char*)ws;
    const char* spb = (const char*)sP;

    // coords prefetch (software pipeline, depth 1)
    float cx = coords[3*(wgbase + (wave<<4) + p) + 0];
    float cy = coords[3*(wgbase + (wave<<4) + p) + 1];
    float cz = coords[3*(wgbase + (wave<<4) + p) + 2];

    for (int g = wave; g < 256; g += 16) {
        const int pbase = wgbase + (g << 4);
        const int gn = (g + 16 < 256) ? g + 16 : g;
        const int ptn = wgbase + (gn << 4) + p;
        const float nx = coords[3*ptn + 0];
        const float ny = coords[3*ptn + 1];
        const float nz = coords[3*ptn + 2];

        int lidx[3], pidx[3], vidx[3];
        float lww[3], lwm[3], pww[3], pwm[3], vww[3], vwm[3];
        {
            const float uu[3] = { (cx+1.f)*0.5f, (cy+1.f)*0.5f, (cz+1.f)*0.5f };
            #pragma unroll
            for (int c = 0; c < 3; ++c) {
                float pos = fminf(fmaxf(uu[c]*511.f, 0.f), 511.f);
                float i0 = fminf(floorf(pos), 510.f);
                lidx[c] = (int)i0; lww[c] = pos - i0; lwm[c] = 1.f - lww[c];
                float pq = fminf(fmaxf(uu[c]*19.f, 0.f), 19.f);
                float pi0 = fminf(floorf(pq), 18.f);
                pidx[c] = (int)pi0; pww[c] = pq - pi0; pwm[c] = 1.f - pww[c];
                float vq = fminf(fmaxf(uu[c]*4.f, 0.f), 4.f);
                float vi0 = fminf(floorf(vq), 3.f);
                vidx[c] = (int)vi0; vww[c] = vq - vi0; vwm[c] = 1.f - vww[c];
            }
        }
        // line byte bases: [c][i0] block = 256 B; tap1 at +128; cc chunk at +64
        int laddr[3];
        #pragma unroll
        for (int c = 0; c < 3; ++c)
            laddr[c] = (c*511 + lidx[c])*256 + fg*16;
        // planes xy,yz: corner weights + swizzled LDS addresses
        float wqf[2][4];
        int paddr[2][4];
        #pragma unroll
        for (int pp = 0; pp < 2; ++pp) {
            const int a = (pp==0)?0:1;    // gx axis (col)
            const int b = (pp==0)?1:2;    // gy axis (row)
            wqf[pp][0] = pwm[b]*pwm[a]; wqf[pp][1] = pwm[b]*pww[a];
            wqf[pp][2] = pww[b]*pwm[a]; wqf[pp][3] = pww[b]*pww[a];
            const int r00 = pidx[b]*20 + pidx[a];
            const int roff[4] = {0, 1, 20, 21};
            #pragma unroll
            for (int k = 0; k < 4; ++k) {
                const int r = r00 + roff[k];
                paddr[pp][k] = pp*51200 + r*128 + ((fg ^ (r & 7)) << 4);
            }
        }
        // plane zx: gx=z (col), gy=x (row)
        int prow[4];
        h2 wq2b[4];
        {
            wq2b[0] = bc(pwm[0]*pwm[2]); wq2b[1] = bc(pwm[0]*pww[2]);
            wq2b[2] = bc(pww[0]*pwm[2]); wq2b[3] = bc(pww[0]*pww[2]);
            const int r00 = pidx[0]*20 + pidx[2];
            const int roff[4] = {0, 1, 20, 21};
            #pragma unroll
            for (int k = 0; k < 4; ++k) {
#if HAS_FP8
                prow[k] = PZ8B + (r00 + roff[k])*72;
#else
                const int r = r00 + roff[k];
                prow[k] = WS_PLANE_DW*4 + 2*51200 + r*128 + ((fg ^ (r & 7)) << 4);
#endif
            }
        }
        // volume: LDS, padded rows (144 B)
        const int vox00 = (vidx[2]*5 + vidx[1])*5 + vidx[0];
        const int vb = VOLB + vox00*144 + fg*16;
        float wvf[8];
        #pragma unroll
        for (int dz = 0; dz < 2; ++dz)
            #pragma unroll
            for (int dy = 0; dy < 2; ++dy)
                #pragma unroll
                for (int dx = 0; dx < 2; ++dx)
                    wvf[dz*4+dy*2+dx] = (dz?vww[2]:vwm[2])*(dy?vww[1]:vwm[1])*(dx?vww[0]:vwm[0]);

        // h2 weight broadcasts
        h2 wlm[3], wlw[3], wqb[2][4], wvb[8];
        #pragma unroll
        for (int c = 0; c < 3; ++c) { wlm[c] = bc(lwm[c]); wlw[c] = bc(lww[c]); }
        #pragma unroll
        for (int pp = 0; pp < 2; ++pp)
            #pragma unroll
            for (int k = 0; k < 4; ++k) wqb[pp][k] = bc(wqf[pp][k]);
        #pragma unroll
        for (int t = 0; t < 8; ++t) wvb[t] = bc(wvf[t]);

        union UH { uint4 v; h2 h[4]; };
        h2 comb[2][4];
        #pragma unroll
        for (int cc = 0; cc < 2; ++cc) {
            const int co = cc * 64;
            // ---- global loads first: lines (6 b128, the only L2 traffic) ----
            UH X0, X1, Y0, Y1, Z0, Z1;
            X0.v = *(const uint4*)(wsb + laddr[0] + co);
            X1.v = *(const uint4*)(wsb + laddr[0] + co + 128);
            Y0.v = *(const uint4*)(wsb + laddr[1] + co);
            Y1.v = *(const uint4*)(wsb + laddr[1] + co + 128);
            Z0.v = *(const uint4*)(wsb + laddr[2] + co);
            Z1.v = *(const uint4*)(wsb + laddr[2] + co + 128);
            // ---- volume from LDS while globals fly ----
            UH V[8];
            #pragma unroll
            for (int dz = 0; dz < 2; ++dz)
                #pragma unroll
                for (int dy = 0; dy < 2; ++dy)
                    #pragma unroll
                    for (int dx = 0; dx < 2; ++dx)
                        V[dz*4+dy*2+dx].v =
                            *(const uint4*)(spb + vb + (dz*25+dy*5+dx)*144 + co);
            #pragma unroll
            for (int j = 0; j < 4; ++j) {
                h2 s = V[0].h[j]*wvb[0] + V[1].h[j]*wvb[1]
                     + V[2].h[j]*wvb[2] + V[3].h[j]*wvb[3];
                s += V[4].h[j]*wvb[4] + V[5].h[j]*wvb[5]
                   + V[6].h[j]*wvb[6] + V[7].h[j]*wvb[7];
                comb[cc][j] = s;
            }
            // ---- plane zx: fp8 from LDS (decode) or f16 from global ----
            h2 pa2[4];
            #pragma unroll
            for (int j = 0; j < 4; ++j) pa2[j] = (h2){(half_t)0.f, (half_t)0.f};
#if HAS_FP8
            #pragma unroll
            for (int k = 0; k < 4; ++k) {
                const uint2 q = *(const uint2*)(spb + prow[k] + cc*32 + fg*8);
                f32x2 e0 = __builtin_amdgcn_cvt_pk_f32_fp8((int)q.x, false);
                f32x2 e1 = __builtin_amdgcn_cvt_pk_f32_fp8((int)q.x, true);
                f32x2 e2 = __builtin_amdgcn_cvt_pk_f32_fp8((int)q.y, false);
                f32x2 e3 = __builtin_amdgcn_cvt_pk_f32_fp8((int)q.y, true);
                h2 ha = pkrtz(e0.x, e0.y);
                h2 hb = pkrtz(e1.x, e1.y);
                h2 hc = pkrtz(e2.x, e2.y);
                h2 hd = pkrtz(e3.x, e3.y);
                pa2[0] += ha*wq2b[k]; pa2[1] += hb*wq2b[k];
                pa2[2] += hc*wq2b[k]; pa2[3] += hd*wq2b[k];
            }
#else
            {
                UH q0, q1, q2, q3;
                q0.v = *(const uint4*)(wsb + (prow[0] ^ co));
                q1.v = *(const uint4*)(wsb + (prow[1] ^ co));
                q2.v = *(const uint4*)(wsb + (prow[2] ^ co));
                q3.v = *(const uint4*)(wsb + (prow[3] ^ co));
                #pragma unroll
                for (int j = 0; j < 4; ++j)
                    pa2[j] = q0.h[j]*wq2b[0] + q1.h[j]*wq2b[1]
                           + q2.h[j]*wq2b[2] + q3.h[j]*wq2b[3];
            }
#endif
            // ---- line lerps (needs globals) ----
            h2 fx[4], fy[4], fz[4];
            #pragma unroll
            for (int j = 0; j < 4; ++j) {
                fx[j] = X0.h[j]*wlm[0] + X1.h[j]*wlw[0];
                fy[j] = Y0.h[j]*wlm[1] + Y1.h[j]*wlw[1];
                fz[j] = Z0.h[j]*wlm[2] + Z1.h[j]*wlw[2];
            }
            #pragma unroll
            for (int j = 0; j < 4; ++j) comb[cc][j] += fx[j]*fy[j]*fz[j];
            // ---- planes xy,yz from LDS ----
            #pragma unroll
            for (int pp = 0; pp < 2; ++pp) {
                UH r0, r1, r2, r3;
                r0.v = *(const uint4*)(spb + (paddr[pp][0] ^ co));
                r1.v = *(const uint4*)(spb + (paddr[pp][1] ^ co));
                r2.v = *(const uint4*)(spb + (paddr[pp][2] ^ co));
                r3.v = *(const uint4*)(spb + (paddr[pp][3] ^ co));
                #pragma unroll
                for (int j = 0; j < 4; ++j) {
                    h2 pa = r0.h[j]*wqb[pp][0] + r1.h[j]*wqb[pp][1]
                          + r2.h[j]*wqb[pp][2] + r3.h[j]*wqb[pp][3];
                    const h2 lf = (pp==0) ? fz[j] : fx[j];
                    comb[cc][j] += pa * lf;
                }
            }
            // ---- plane zx contribution ----
            #pragma unroll
            for (int j = 0; j < 4; ++j) comb[cc][j] += pa2[j] * fy[j];
        }
        // MLP layer 1 via f16 MFMA; comb is already the A-fragment
        union AF { f16x8 v; h2 h[4]; } A0, A1;
        #pragma unroll
        for (int j = 0; j < 4; ++j) { A0.h[j] = comb[0][j]; A1.h[j] = comb[1][j]; }
        f32x4 acc0 = {0.f,0.f,0.f,0.f};
        f32x4 acc1 = {0.f,0.f,0.f,0.f};
        f32x4 acc2 = {0.f,0.f,0.f,0.f};
        f32x4 acc3 = {0.f,0.f,0.f,0.f};
        acc0 = __builtin_amdgcn_mfma_f32_16x16x32_f16(A0.v, wfrag[0][0], acc0, 0, 0, 0);
        acc0 = __builtin_amdgcn_mfma_f32_16x16x32_f16(A1.v, wfrag[0][1], acc0, 0, 0, 0);
        acc1 = __builtin_amdgcn_mfma_f32_16x16x32_f16(A0.v, wfrag[1][0], acc1, 0, 0, 0);
        acc1 = __builtin_amdgcn_mfma_f32_16x16x32_f16(A1.v, wfrag[1][1], acc1, 0, 0, 0);
        acc2 = __builtin_amdgcn_mfma_f32_16x16x32_f16(A0.v, wfrag[2][0], acc2, 0, 0, 0);
        acc2 = __builtin_amdgcn_mfma_f32_16x16x32_f16(A1.v, wfrag[2][1], acc2, 0, 0, 0);
        acc3 = __builtin_amdgcn_mfma_f32_16x16x32_f16(A0.v, wfrag[3][0], acc3, 0, 0, 0);
        acc3 = __builtin_amdgcn_mfma_f32_16x16x32_f16(A1.v, wfrag[3][1], acc3, 0, 0, 0);
        // layer 2: relu + dot with w2; reduce across the 16 C-layout columns
        float sr[4];
        #pragma unroll
        for (int r = 0; r < 4; ++r) {
            float s = fmaxf(acc0[r] + b1v[0], 0.f) * w2v[0];
            s = fmaf(fmaxf(acc1[r] + b1v[1], 0.f), w2v[1], s);
            s = fmaf(fmaxf(acc2[r] + b1v[2], 0.f), w2v[2], s);
            s = fmaf(fmaxf(acc3[r] + b1v[3], 0.f), w2v[3], s);
            sr[r] = s;
        }
        #pragma unroll
        for (int m = 1; m <= 8; m <<= 1) {
            #pragma unroll
            for (int r = 0; r < 4; ++r) sr[r] += __shfl_xor(sr[r], m, 64);
        }
        if (p == 0) {
            float4 o;
            o.x = sr[0] + b2v;
            o.y = sr[1] + b2v;
            o.z = sr[2] + b2v;
            o.w = sr[3] + b2v;
            *(float4*)(out + pbase + (fg << 2)) = o;
        }
        cx = nx; cy = ny; cz = nz;
    }
}

// ---------------------------------------------------------------------------
// Fallback (only if ws_size is too small): slow but correct, thread-per-point.
// ---------------------------------------------------------------------------
__global__ __launch_bounds__(256) void ga_naive(
    const float* __restrict__ coords,
    const float* __restrict__ lx, const float* __restrict__ ly, const float* __restrict__ lz,
    const float* __restrict__ pxy, const float* __restrict__ pyz, const float* __restrict__ pzx,
    const float* __restrict__ vol,
    const float* __restrict__ w1, const float* __restrict__ b1,
    const float* __restrict__ w2, const float* __restrict__ b2,
    float* __restrict__ out)
{
    const int n = blockIdx.x * blockDim.x + threadIdx.x;
    if (n >= NPTS) return;
    int lidx[3], pidx[3], vidx[3];
    float lww[3], lwm[3], pww[3], pwm[3], vww[3], vwm[3];
    for (int c = 0; c < 3; ++c) {
        const float cv = coords[3*n + c];
        const float u = (cv + 1.f)*0.5f;
        float pos = fminf(fmaxf(u*511.f, 0.f), 511.f);
        float i0 = fminf(floorf(pos), 510.f);
        lidx[c] = (int)i0; lww[c] = pos - i0; lwm[c] = 1.f - lww[c];
        float pq = fminf(fmaxf(u*19.f, 0.f), 19.f);
        float pi0 = fminf(floorf(pq), 18.f);
        pidx[c] = (int)pi0; pww[c] = pq - pi0; pwm[c] = 1.f - pww[c];
        float vq = fminf(fmaxf(u*4.f, 0.f), 4.f);
        float vi0 = fminf(floorf(vq), 3.f);
        vidx[c] = (int)vi0; vww[c] = vq - vi0; vwm[c] = 1.f - vww[c];
    }
    float comb[64];
    for (int f = 0; f < 64; ++f) {
        const float fxv = lwm[0]*lx[f*512+lidx[0]] + lww[0]*lx[f*512+lidx[0]+1];
        const float fyv = lwm[1]*ly[f*512+lidx[1]] + lww[1]*ly[f*512+lidx[1]+1];
        const float fzv = lwm[2]*lz[f*512+lidx[2]] + lww[2]*lz[f*512+lidx[2]+1];
        const int bxy = f*400 + pidx[1]*20 + pidx[0];
        const float pxyv = pwm[1]*pwm[0]*pxy[bxy]    + pwm[1]*pww[0]*pxy[bxy+1]
                         + pww[1]*pwm[0]*pxy[bxy+20] + pww[1]*pww[0]*pxy[bxy+21];
        const int byz = f*400 + pidx[2]*20 + pidx[1];
        const float pyzv = pwm[2]*pwm[1]*pyz[byz]    + pwm[2]*pww[1]*pyz[byz+1]
                         + pww[2]*pwm[1]*pyz[byz+20] + pww[2]*pww[1]*pyz[byz+21];
        const int bzx = f*400 + pidx[0]*20 + pidx[2];
        const float pzxv = pwm[0]*pwm[2]*pzx[bzx]    + pwm[0]*pww[2]*pzx[bzx+1]
                         + pww[0]*pwm[2]*pzx[bzx+20] + pww[0]*pww[2]*pzx[bzx+21];
        const int bv = f*125 + (vidx[2]*5 + vidx[1])*5 + vidx[0];
        float vv = 0.f;
        for (int dz = 0; dz < 2; ++dz)
            for (int dy = 0; dy < 2; ++dy)
                for (int dx = 0; dx < 2; ++dx) {
                    const float w = (dz ? vww[2] : vwm[2]) * (dy ? vww[1] : vwm[1]) * (dx ? vww[0] : vwm[0]);
                    vv += w * vol[bv + dz*25 + dy*5 + dx];
                }
        comb[f] = fxv*fyv*fzv + pxyv*fzv + pyzv*fxv + pzxv*fyv + vv;
    }
    float o = b2[0];
    for (int gg = 0; gg < 64; ++gg) {
        float h = b1[gg];
        for (int f = 0; f < 64; ++f) h = fmaf(comb[f], w1[gg*64 + f], h);
        o = fmaf(fmaxf(h, 0.f), w2[gg], o);
    }
    out[n] = o;
}

extern "C" void kernel_launch(void* const* d_in, const int* in_sizes, int n_in,
                              void* d_out, int out_size, void* d_ws, size_t ws_size,
                              hipStream_t stream)
{
    const float* coords = (const float*)d_in[0];
    const float* lx  = (const float*)d_in[1];
    const float* ly  = (const float*)d_in[2];
    const float* lz  = (const float*)d_in[3];
    const float* pxy = (const float*)d_in[4];
    const float* pyz = (const float*)d_in[5];
    const float* pzx = (const float*)d_in[6];
    const float* vol = (const float*)d_in[7];
    const float* w1  = (const float*)d_in[8];
    const float* b1  = (const float*)d_in[9];
    const float* w2  = (const float*)d_in[10];
    const float* b2  = (const float*)d_in[11];
    float* out = (float*)d_out;
    if (ws_size >= (size_t)WS_TOTAL_BYTES) {
        u32* ws = (u32*)d_ws;
        ga_prep<<<dim3(600), dim3(256), 0, stream>>>(lx, ly, lz, pxy, pyz, pzx, vol, ws);
        ga_main<<<dim3(256), dim3(1024), 0, stream>>>(coords, w1, b1, w2, b2, ws, out);
    } else {
        ga_naive<<<dim3(4096), dim3(256), 0, stream>>>(coords, lx, ly, lz, pxy, pyz, pzx, vol,
                                                       w1, b1, w2, b2, out);
    }
}

// Round 8
// 203.869 us; speedup vs baseline: 3.7713x; 1.0722x over previous
//
#include <hip/hip_runtime.h>

typedef unsigned int u32;
typedef unsigned short u16;
typedef _Float16 half_t;
typedef half_t h2   __attribute__((ext_vector_type(2)));
typedef half_t f16x8 __attribute__((ext_vector_type(8)));
typedef float  f32x4 __attribute__((ext_vector_type(4)));
typedef float  f32x2 __attribute__((ext_vector_type(2)));
typedef __fp16 fp16v2 __attribute__((ext_vector_type(2)));

#define NPTS 1048576

#if defined(__has_builtin)
#if __has_builtin(__builtin_amdgcn_cvt_pk_f32_fp8) && __has_builtin(__builtin_amdgcn_cvt_pk_fp8_f32) && __has_builtin(__builtin_amdgcn_cvt_pkrtz)
#define HAS_FP8 1
#endif
#endif
#ifndef HAS_FP8
#define HAS_FP8 0
#endif

// workspace dword layout (built by ga_prep from fp32 inputs)
#if HAS_FP8
#define WS_LINE_SZ  49056   // 3*511*32 dw: [c][i0][f-pair fp8: f0t0 f0t1 f1t0 f1t1] (128 B/i0)
#else
#define WS_LINE_SZ  98112   // 3*511*2*32 dw: [c][i0][tap][fpair] f16 (256 B/i0)
#endif
#define WS_VOL_DW   (WS_LINE_SZ)            // 125*32 = 4000 dw: [vox][fpair] f16
#define WS_PLANE_DW (WS_VOL_DW + 4000)      // 3*400*32 dw: [pp][row][swizzled chunk][fpair] f16
#define WS_PZX8_DW  (WS_PLANE_DW + 38400)   // 400*18 dw: [row][fp8 x64 + pad]
#if HAS_FP8
#define WS_TOTAL_DW (WS_PZX8_DW + 7200)
#else
#define WS_TOTAL_DW (WS_PZX8_DW)
#endif
#define WS_TOTAL_BYTES (WS_TOTAL_DW * 4)

// LDS layout (dwords): planes xy,yz at 0 (25600 dw); volume at 25600 (125 rows x 36 dw);
// pzx-fp8 at 30100 (400 rows x 18 dw). Total 37300 dw = 149,200 B -> 1 block/CU.
#define LDS_VOL_DW   25600
#define LDS_PZ8_DW   30100
#define LDS_TOTAL_DW 37300
#define VOLB         (LDS_VOL_DW*4)    // 102400
#define PZ8B         (LDS_PZ8_DW*4)    // 120400

__device__ __forceinline__ u32 pkh(float a, float b) {
    union { h2 h; u32 u; } r;
    r.h = (h2){(half_t)a, (half_t)b};
    return r.u;
}
__device__ __forceinline__ h2 bc(float w) {
    half_t h = (half_t)w;
    return (h2){h, h};
}
__device__ __forceinline__ h2 pkrtz(float a, float b) {
    union { fp16v2 f; h2 h; } r;
    r.f = __builtin_amdgcn_cvt_pkrtz(a, b);
    return r.h;
}

union U4 { uint4 v; u32 s[4]; };

// ---------------------------------------------------------------------------
// Prep: fp32 inputs -> fp8 line tables + f16 vol/plane tables + fp8 pzx.
// ---------------------------------------------------------------------------
__global__ __launch_bounds__(256) void ga_prep(
    const float* __restrict__ lx, const float* __restrict__ ly, const float* __restrict__ lz,
    const float* __restrict__ pxy, const float* __restrict__ pyz, const float* __restrict__ pzx,
    const float* __restrict__ vol, u32* __restrict__ ws)
{
    const int stride = gridDim.x * blockDim.x;
    for (int t = blockIdx.x * blockDim.x + threadIdx.x; t < WS_TOTAL_DW; t += stride) {
        if (t < WS_LINE_SZ) {
#if HAS_FP8
            // fp8 lines: dw d of row i0 = features 2d,2d+1, bytes (f0t0,f0t1,f1t0,f1t1)
            const int c  = t / 16352;           // 511*32
            const int r  = t - c * 16352;
            const int i0 = r >> 5;              // 0..510
            const int d  = r & 31;
            const float* L = (c == 0) ? lx : (c == 1) ? ly : lz;
            const int f0 = 2*d, f1 = 2*d + 1;
            int v = 0;
            v = __builtin_amdgcn_cvt_pk_fp8_f32(L[f0*512 + i0], L[f0*512 + i0 + 1], v, false);
            v = __builtin_amdgcn_cvt_pk_fp8_f32(L[f1*512 + i0], L[f1*512 + i0 + 1], v, true);
            ws[t] = (u32)v;
#else
            const int c  = t / 32704;           // 511*64
            const int r  = t - c * 32704;
            const int i0 = r >> 6;
            const int w  = r & 63;
            const int tap = w >> 5;
            const int fp  = w & 31;
            const float* L = (c == 0) ? lx : (c == 1) ? ly : lz;
            ws[t] = pkh(L[(2*fp)*512 + i0 + tap], L[(2*fp+1)*512 + i0 + tap]);
#endif
        } else if (t < WS_PLANE_DW) {
            const int r = t - WS_VOL_DW;
            const int vox = r >> 5;
            const int fp  = r & 31;
            ws[t] = pkh(vol[(2*fp)*125 + vox], vol[(2*fp+1)*125 + vox]);
        } else if (t < WS_PZX8_DW) {
            const int r  = t - WS_PLANE_DW;
            const int pp = r / 12800;
            const int rr = r - pp * 12800;
            const int row = rr >> 5;            // 0..399 (= y*20+x)
            const int c   = rr & 31;            // fpair index
            const int chunk = c >> 2;
            const int ci    = c & 3;
            const int pos = ((chunk ^ (row & 7)) << 2) + ci;  // XOR swizzle
            const float* P = (pp == 0) ? pxy : (pp == 1) ? pyz : pzx;
            const int f = c * 2;
            ws[WS_PLANE_DW + pp*12800 + (row << 5) + pos] =
                pkh(P[f*400 + row], P[(f+1)*400 + row]);
        } else {
#if HAS_FP8
            const int t2 = t - WS_PZX8_DW;
            const int row = t2 / 18;
            const int d   = t2 - row * 18;
            u32 v = 0;
            if (d < 16) {
                const int f0 = d * 4;
                int dw = 0;
                dw = __builtin_amdgcn_cvt_pk_fp8_f32(pzx[(f0+0)*400+row], pzx[(f0+1)*400+row], dw, false);
                dw = __builtin_amdgcn_cvt_pk_fp8_f32(pzx[(f0+2)*400+row], pzx[(f0+3)*400+row], dw, true);
                v = (u32)dw;
            }
            ws[t] = v;
#endif
        }
    }
}

// ---------------------------------------------------------------------------
// Main: lane = (point p = lane&15, feature group fg = lane>>4).
// LDS: planes xy,yz (f16) + padded volume (f16) + pzx (fp8).
// Lines from L2 as fp8 (one 16B load per axis per cc covers both taps):
// 6.4 divergent lines/point (was 12.4).
// ---------------------------------------------------------------------------
__global__ __launch_bounds__(1024, 4) void ga_main(
    const float* __restrict__ coords,
    const float* __restrict__ w1,
    const float* __restrict__ b1,
    const float* __restrict__ w2,
    const float* __restrict__ b2,
    const u32* __restrict__ ws,
    float* __restrict__ out)
{
    __shared__ u32 sP[LDS_TOTAL_DW];   // 149,200 B
    const int tid = threadIdx.x;
    {
        const uint4* src = (const uint4*)(ws + WS_PLANE_DW);
        uint4* dst = (uint4*)sP;
        #pragma unroll
        for (int i = 0; i < 7; ++i) {
            int idx = tid + i * 1024;
            if (idx < 6400) dst[idx] = src[idx];
        }
        if (tid < 1000) {
            const int vox = tid >> 3, ch = tid & 7;
            ((uint4*)(sP + LDS_VOL_DW))[vox*9 + ch] = ((const uint4*)(ws + WS_VOL_DW))[tid];
        }
#if HAS_FP8
        #pragma unroll
        for (int i = 0; i < 2; ++i) {
            int idx = tid + i * 1024;
            if (idx < 1800)
                ((uint4*)(sP + LDS_PZ8_DW))[idx] = ((const uint4*)(ws + WS_PZX8_DW))[idx];
        }
#endif
    }
    __syncthreads();

    const int lane = tid & 63;
    const int wave = tid >> 6;       // 0..15
    const int p    = lane & 15;
    const int fg   = lane >> 4;      // 0..3
    const int wgbase = blockIdx.x << 12;   // 4096 points per workgroup

    // w1 B-fragments (f16)
    f16x8 wfrag[4][2];
    #pragma unroll
    for (int t = 0; t < 4; ++t) {
        #pragma unroll
        for (int h = 0; h < 2; ++h) {
            const float* src = w1 + ((16*t + p)*64 + h*32 + fg*8);
            f16x8 w;
            #pragma unroll
            for (int e = 0; e < 8; ++e) w[e] = (half_t)src[e];
            wfrag[t][h] = w;
        }
    }
    float b1v[4], w2v[4];
    #pragma unroll
    for (int t = 0; t < 4; ++t) { b1v[t] = b1[16*t + p]; w2v[t] = w2[16*t + p]; }
    const float b2v = b2[0];

    const char* wsb = (const char*)ws;
    const char* spb = (const char*)sP;

    // coords prefetch (software pipeline, depth 1)
    float cx = coords[3*(wgbase + (wave<<4) + p) + 0];
    float cy = coords[3*(wgbase + (wave<<4) + p) + 1];
    float cz = coords[3*(wgbase + (wave<<4) + p) + 2];

    for (int g = wave; g < 256; g += 16) {
        const int pbase = wgbase + (g << 4);
        const int gn = (g + 16 < 256) ? g + 16 : g;
        const int ptn = wgbase + (gn << 4) + p;
        const float nx = coords[3*ptn + 0];
        const float ny = coords[3*ptn + 1];
        const float nz = coords[3*ptn + 2];

        int lidx[3], pidx[3], vidx[3];
        float lww[3], lwm[3], pww[3], pwm[3], vww[3], vwm[3];
        {
            const float uu[3] = { (cx+1.f)*0.5f, (cy+1.f)*0.5f, (cz+1.f)*0.5f };
            #pragma unroll
            for (int c = 0; c < 3; ++c) {
                float pos = fminf(fmaxf(uu[c]*511.f, 0.f), 511.f);
                float i0 = fminf(floorf(pos), 510.f);
                lidx[c] = (int)i0; lww[c] = pos - i0; lwm[c] = 1.f - lww[c];
                float pq = fminf(fmaxf(uu[c]*19.f, 0.f), 19.f);
                float pi0 = fminf(floorf(pq), 18.f);
                pidx[c] = (int)pi0; pww[c] = pq - pi0; pwm[c] = 1.f - pww[c];
                float vq = fminf(fmaxf(uu[c]*4.f, 0.f), 4.f);
                float vi0 = fminf(floorf(vq), 3.f);
                vidx[c] = (int)vi0; vww[c] = vq - vi0; vwm[c] = 1.f - vww[c];
            }
        }
        // line byte bases
        int laddr[3];
        #pragma unroll
        for (int c = 0; c < 3; ++c)
#if HAS_FP8
            laddr[c] = (c*511 + lidx[c])*128 + fg*16;   // fp8: 128 B/i0, cc chunk at +64
#else
            laddr[c] = (c*511 + lidx[c])*256 + fg*16;   // f16: 256 B/i0, tap1 +128, cc +64
#endif
        // planes xy,yz: corner weights + swizzled LDS addresses
        float wqf[2][4];
        int paddr[2][4];
        #pragma unroll
        for (int pp = 0; pp < 2; ++pp) {
            const int a = (pp==0)?0:1;    // gx axis (col)
            const int b = (pp==0)?1:2;    // gy axis (row)
            wqf[pp][0] = pwm[b]*pwm[a]; wqf[pp][1] = pwm[b]*pww[a];
            wqf[pp][2] = pww[b]*pwm[a]; wqf[pp][3] = pww[b]*pww[a];
            const int r00 = pidx[b]*20 + pidx[a];
            const int roff[4] = {0, 1, 20, 21};
            #pragma unroll
            for (int k = 0; k < 4; ++k) {
                const int r = r00 + roff[k];
                paddr[pp][k] = pp*51200 + r*128 + ((fg ^ (r & 7)) << 4);
            }
        }
        // plane zx: gx=z (col), gy=x (row)
        int prow[4];
        h2 wq2b[4];
        {
            wq2b[0] = bc(pwm[0]*pwm[2]); wq2b[1] = bc(pwm[0]*pww[2]);
            wq2b[2] = bc(pww[0]*pwm[2]); wq2b[3] = bc(pww[0]*pww[2]);
            const int r00 = pidx[0]*20 + pidx[2];
            const int roff[4] = {0, 1, 20, 21};
            #pragma unroll
            for (int k = 0; k < 4; ++k) {
#if HAS_FP8
                prow[k] = PZ8B + (r00 + roff[k])*72;
#else
                const int r = r00 + roff[k];
                prow[k] = WS_PLANE_DW*4 + 2*51200 + r*128 + ((fg ^ (r & 7)) << 4);
#endif
            }
        }
        // volume: LDS, padded rows (144 B)
        const int vox00 = (vidx[2]*5 + vidx[1])*5 + vidx[0];
        const int vb = VOLB + vox00*144 + fg*16;
        float wvf[8];
        #pragma unroll
        for (int dz = 0; dz < 2; ++dz)
            #pragma unroll
            for (int dy = 0; dy < 2; ++dy)
                #pragma unroll
                for (int dx = 0; dx < 2; ++dx)
                    wvf[dz*4+dy*2+dx] = (dz?vww[2]:vwm[2])*(dy?vww[1]:vwm[1])*(dx?vww[0]:vwm[0]);

        // h2 weight broadcasts
        h2 wqb[2][4], wvb[8];
        #pragma unroll
        for (int pp = 0; pp < 2; ++pp)
            #pragma unroll
            for (int k = 0; k < 4; ++k) wqb[pp][k] = bc(wqf[pp][k]);
        #pragma unroll
        for (int t = 0; t < 8; ++t) wvb[t] = bc(wvf[t]);
#if !HAS_FP8
        h2 wlm[3], wlw[3];
        #pragma unroll
        for (int c = 0; c < 3; ++c) { wlm[c] = bc(lwm[c]); wlw[c] = bc(lww[c]); }
#endif

        union UH { uint4 v; h2 h[4]; };
        h2 comb[2][4];
        #pragma unroll
        for (int cc = 0; cc < 2; ++cc) {
            const int co = cc * 64;
            // ---- global loads first: lines (3 b128 fp8 / 6 b128 f16) ----
#if HAS_FP8
            U4 LX, LY, LZ;
            LX.v = *(const uint4*)(wsb + laddr[0] + co);
            LY.v = *(const uint4*)(wsb + laddr[1] + co);
            LZ.v = *(const uint4*)(wsb + laddr[2] + co);
#else
            UH X0, X1, Y0, Y1, Z0, Z1;
            X0.v = *(const uint4*)(wsb + laddr[0] + co);
            X1.v = *(const uint4*)(wsb + laddr[0] + co + 128);
            Y0.v = *(const uint4*)(wsb + laddr[1] + co);
            Y1.v = *(const uint4*)(wsb + laddr[1] + co + 128);
            Z0.v = *(const uint4*)(wsb + laddr[2] + co);
            Z1.v = *(const uint4*)(wsb + laddr[2] + co + 128);
#endif
            // ---- volume from LDS while globals fly ----
            UH V[8];
            #pragma unroll
            for (int dz = 0; dz < 2; ++dz)
                #pragma unroll
                for (int dy = 0; dy < 2; ++dy)
                    #pragma unroll
                    for (int dx = 0; dx < 2; ++dx)
                        V[dz*4+dy*2+dx].v =
                            *(const uint4*)(spb + vb + (dz*25+dy*5+dx)*144 + co);
            #pragma unroll
            for (int j = 0; j < 4; ++j) {
                h2 s = V[0].h[j]*wvb[0] + V[1].h[j]*wvb[1]
                     + V[2].h[j]*wvb[2] + V[3].h[j]*wvb[3];
                s += V[4].h[j]*wvb[4] + V[5].h[j]*wvb[5]
                   + V[6].h[j]*wvb[6] + V[7].h[j]*wvb[7];
                comb[cc][j] = s;
            }
            // ---- plane zx: fp8 from LDS (decode) or f16 from global ----
            h2 pa2[4];
            #pragma unroll
            for (int j = 0; j < 4; ++j) pa2[j] = (h2){(half_t)0.f, (half_t)0.f};
#if HAS_FP8
            #pragma unroll
            for (int k = 0; k < 4; ++k) {
                const uint2 q = *(const uint2*)(spb + prow[k] + cc*32 + fg*8);
                f32x2 e0 = __builtin_amdgcn_cvt_pk_f32_fp8((int)q.x, false);
                f32x2 e1 = __builtin_amdgcn_cvt_pk_f32_fp8((int)q.x, true);
                f32x2 e2 = __builtin_amdgcn_cvt_pk_f32_fp8((int)q.y, false);
                f32x2 e3 = __builtin_amdgcn_cvt_pk_f32_fp8((int)q.y, true);
                h2 ha = pkrtz(e0.x, e0.y);
                h2 hb = pkrtz(e1.x, e1.y);
                h2 hc = pkrtz(e2.x, e2.y);
                h2 hd = pkrtz(e3.x, e3.y);
                pa2[0] += ha*wq2b[k]; pa2[1] += hb*wq2b[k];
                pa2[2] += hc*wq2b[k]; pa2[3] += hd*wq2b[k];
            }
#else
            {
                UH q0, q1, q2, q3;
                q0.v = *(const uint4*)(wsb + (prow[0] ^ co));
                q1.v = *(const uint4*)(wsb + (prow[1] ^ co));
                q2.v = *(const uint4*)(wsb + (prow[2] ^ co));
                q3.v = *(const uint4*)(wsb + (prow[3] ^ co));
                #pragma unroll
                for (int j = 0; j < 4; ++j)
                    pa2[j] = q0.h[j]*wq2b[0] + q1.h[j]*wq2b[1]
                           + q2.h[j]*wq2b[2] + q3.h[j]*wq2b[3];
            }
#endif
            // ---- line lerps ----
            h2 fx[4], fy[4], fz[4];
#if HAS_FP8
            #pragma unroll
            for (int i = 0; i < 4; ++i) {
                f32x2 xa = __builtin_amdgcn_cvt_pk_f32_fp8((int)LX.s[i], false);
                f32x2 xb = __builtin_amdgcn_cvt_pk_f32_fp8((int)LX.s[i], true);
                fx[i] = pkrtz(xa.x*lwm[0] + xa.y*lww[0], xb.x*lwm[0] + xb.y*lww[0]);
                f32x2 ya = __builtin_amdgcn_cvt_pk_f32_fp8((int)LY.s[i], false);
                f32x2 yb = __builtin_amdgcn_cvt_pk_f32_fp8((int)LY.s[i], true);
                fy[i] = pkrtz(ya.x*lwm[1] + ya.y*lww[1], yb.x*lwm[1] + yb.y*lww[1]);
                f32x2 za = __builtin_amdgcn_cvt_pk_f32_fp8((int)LZ.s[i], false);
                f32x2 zb = __builtin_amdgcn_cvt_pk_f32_fp8((int)LZ.s[i], true);
                fz[i] = pkrtz(za.x*lwm[2] + za.y*lww[2], zb.x*lwm[2] + zb.y*lww[2]);
            }
#else
            #pragma unroll
            for (int j = 0; j < 4; ++j) {
                fx[j] = X0.h[j]*wlm[0] + X1.h[j]*wlw[0];
                fy[j] = Y0.h[j]*wlm[1] + Y1.h[j]*wlw[1];
                fz[j] = Z0.h[j]*wlm[2] + Z1.h[j]*wlw[2];
            }
#endif
            #pragma unroll
            for (int j = 0; j < 4; ++j) comb[cc][j] += fx[j]*fy[j]*fz[j];
            // ---- planes xy,yz from LDS ----
            #pragma unroll
            for (int pp = 0; pp < 2; ++pp) {
                UH r0, r1, r2, r3;
                r0.v = *(const uint4*)(spb + (paddr[pp][0] ^ co));
                r1.v = *(const uint4*)(spb + (paddr[pp][1] ^ co));
                r2.v = *(const uint4*)(spb + (paddr[pp][2] ^ co));
                r3.v = *(const uint4*)(spb + (paddr[pp][3] ^ co));
                #pragma unroll
                for (int j = 0; j < 4; ++j) {
                    h2 pa = r0.h[j]*wqb[pp][0] + r1.h[j]*wqb[pp][1]
                          + r2.h[j]*wqb[pp][2] + r3.h[j]*wqb[pp][3];
                    const h2 lf = (pp==0) ? fz[j] : fx[j];
                    comb[cc][j] += pa * lf;
                }
            }
            // ---- plane zx contribution ----
            #pragma unroll
            for (int j = 0; j < 4; ++j) comb[cc][j] += pa2[j] * fy[j];
        }
        // MLP layer 1 via f16 MFMA; comb is already the A-fragment
        union AF { f16x8 v; h2 h[4]; } A0, A1;
        #pragma unroll
        for (int j = 0; j < 4; ++j) { A0.h[j] = comb[0][j]; A1.h[j] = comb[1][j]; }
        f32x4 acc0 = {0.f,0.f,0.f,0.f};
        f32x4 acc1 = {0.f,0.f,0.f,0.f};
        f32x4 acc2 = {0.f,0.f,0.f,0.f};
        f32x4 acc3 = {0.f,0.f,0.f,0.f};
        acc0 = __builtin_amdgcn_mfma_f32_16x16x32_f16(A0.v, wfrag[0][0], acc0, 0, 0, 0);
        acc0 = __builtin_amdgcn_mfma_f32_16x16x32_f16(A1.v, wfrag[0][1], acc0, 0, 0, 0);
        acc1 = __builtin_amdgcn_mfma_f32_16x16x32_f16(A0.v, wfrag[1][0], acc1, 0, 0, 0);
        acc1 = __builtin_amdgcn_mfma_f32_16x16x32_f16(A1.v, wfrag[1][1], acc1, 0, 0, 0);
        acc2 = __builtin_amdgcn_mfma_f32_16x16x32_f16(A0.v, wfrag[2][0], acc2, 0, 0, 0);
        acc2 = __builtin_amdgcn_mfma_f32_16x16x32_f16(A1.v, wfrag[2][1], acc2, 0, 0, 0);
        acc3 = __builtin_amdgcn_mfma_f32_16x16x32_f16(A0.v, wfrag[3][0], acc3, 0, 0, 0);
        acc3 = __builtin_amdgcn_mfma_f32_16x16x32_f16(A1.v, wfrag[3][1], acc3, 0, 0, 0);
        // layer 2: relu + dot with w2; reduce across the 16 C-layout columns
        float sr[4];
        #pragma unroll
        for (int r = 0; r < 4; ++r) {
            float s = fmaxf(acc0[r] + b1v[0], 0.f) * w2v[0];
            s = fmaf(fmaxf(acc1[r] + b1v[1], 0.f), w2v[1], s);
            s = fmaf(fmaxf(acc2[r] + b1v[2], 0.f), w2v[2], s);
            s = fmaf(fmaxf(acc3[r] + b1v[3], 0.f), w2v[3], s);
            sr[r] = s;
        }
        #pragma unroll
        for (int m = 1; m <= 8; m <<= 1) {
            #pragma unroll
            for (int r = 0; r < 4; ++r) sr[r] += __shfl_xor(sr[r], m, 64);
        }
        if (p == 0) {
            float4 o;
            o.x = sr[0] + b2v;
            o.y = sr[1] + b2v;
            o.z = sr[2] + b2v;
            o.w = sr[3] + b2v;
            *(float4*)(out + pbase + (fg << 2)) = o;
        }
        cx = nx; cy = ny; cz = nz;
    }
}

// ---------------------------------------------------------------------------
// Fallback (only if ws_size is too small): slow but correct, thread-per-point.
// ---------------------------------------------------------------------------
__global__ __launch_bounds__(256) void ga_naive(
    const float* __restrict__ coords,
    const float* __restrict__ lx, const float* __restrict__ ly, const float* __restrict__ lz,
    const float* __restrict__ pxy, const float* __restrict__ pyz, const float* __restrict__ pzx,
    const float* __restrict__ vol,
    const float* __restrict__ w1, const float* __restrict__ b1,
    const float* __restrict__ w2, const float* __restrict__ b2,
    float* __restrict__ out)
{
    const int n = blockIdx.x * blockDim.x + threadIdx.x;
    if (n >= NPTS) return;
    int lidx[3], pidx[3], vidx[3];
    float lww[3], lwm[3], pww[3], pwm[3], vww[3], vwm[3];
    for (int c = 0; c < 3; ++c) {
        const float cv = coords[3*n + c];
        const float u = (cv + 1.f)*0.5f;
        float pos = fminf(fmaxf(u*511.f, 0.f), 511.f);
        float i0 = fminf(floorf(pos), 510.f);
        lidx[c] = (int)i0; lww[c] = pos - i0; lwm[c] = 1.f - lww[c];
        float pq = fminf(fmaxf(u*19.f, 0.f), 19.f);
        float pi0 = fminf(floorf(pq), 18.f);
        pidx[c] = (int)pi0; pww[c] = pq - pi0; pwm[c] = 1.f - pww[c];
        float vq = fminf(fmaxf(u*4.f, 0.f), 4.f);
        float vi0 = fminf(floorf(vq), 3.f);
        vidx[c] = (int)vi0; vww[c] = vq - vi0; vwm[c] = 1.f - vww[c];
    }
    float comb[64];
    for (int f = 0; f < 64; ++f) {
        const float fxv = lwm[0]*lx[f*512+lidx[0]] + lww[0]*lx[f*512+lidx[0]+1];
        const float fyv = lwm[1]*ly[f*512+lidx[1]] + lww[1]*ly[f*512+lidx[1]+1];
        const float fzv = lwm[2]*lz[f*512+lidx[2]] + lww[2]*lz[f*512+lidx[2]+1];
        const int bxy = f*400 + pidx[1]*20 + pidx[0];
        const float pxyv = pwm[1]*pwm[0]*pxy[bxy]    + pwm[1]*pww[0]*pxy[bxy+1]
                         + pww[1]*pwm[0]*pxy[bxy+20] + pww[1]*pww[0]*pxy[bxy+21];
        const int byz = f*400 + pidx[2]*20 + pidx[1];
        const float pyzv = pwm[2]*pwm[1]*pyz[byz]    + pwm[2]*pww[1]*pyz[byz+1]
                         + pww[2]*pwm[1]*pyz[byz+20] + pww[2]*pww[1]*pyz[byz+21];
        const int bzx = f*400 + pidx[0]*20 + pidx[2];
        const float pzxv = pwm[0]*pwm[2]*pzx[bzx]    + pwm[0]*pww[2]*pzx[bzx+1]
                         + pww[0]*pwm[2]*pzx[bzx+20] + pww[0]*pww[2]*pzx[bzx+21];
        const int bv = f*125 + (vidx[2]*5 + vidx[1])*5 + vidx[0];
        float vv = 0.f;
        for (int dz = 0; dz < 2; ++dz)
            for (int dy = 0; dy < 2; ++dy)
                for (int dx = 0; dx < 2; ++dx) {
                    const float w = (dz ? vww[2] : vwm[2]) * (dy ? vww[1] : vwm[1]) * (dx ? vww[0] : vwm[0]);
                    vv += w * vol[bv + dz*25 + dy*5 + dx];
                }
        comb[f] = fxv*fyv*fzv + pxyv*fzv + pyzv*fxv + pzxv*fyv + vv;
    }
    float o = b2[0];
    for (int gg = 0; gg < 64; ++gg) {
        float h = b1[gg];
        for (int f = 0; f < 64; ++f) h = fmaf(comb[f], w1[gg*64 + f], h);
        o = fmaf(fmaxf(h, 0.f), w2[gg], o);
    }
    out[n] = o;
}

extern "C" void kernel_launch(void* const* d_in, const int* in_sizes, int n_in,
                              void* d_out, int out_size, void* d_ws, size_t ws_size,
                              hipStream_t stream)
{
    const float* coords = (const float*)d_in[0];
    const float* lx  = (const float*)d_in[1];
    const float* ly  = (const float*)d_in[2];
    const float* lz  = (const float*)d_in[3];
    const float* pxy = (const float*)d_in[4];
    const float* pyz = (const float*)d_in[5];
    const float* pzx = (const float*)d_in[6];
    const float* vol = (const float*)d_in[7];
    const float* w1  = (const float*)d_in[8];
    const float* b1  = (const float*)d_in[9];
    const float* w2  = (const float*)d_in[10];
    const float* b2  = (const float*)d_in[11];
    float* out = (float*)d_out;
    if (ws_size >= (size_t)WS_TOTAL_BYTES) {
        u32* ws = (u32*)d_ws;
        ga_prep<<<dim3(400), dim3(256), 0, stream>>>(lx, ly, lz, pxy, pyz, pzx, vol, ws);
        ga_main<<<dim3(256), dim3(1024), 0, stream>>>(coords, w1, b1, w2, b2, ws, out);
    } else {
        ga_naive<<<dim3(4096), dim3(256), 0, stream>>>(coords, lx, ly, lz, pxy, pyz, pzx, vol,
                                                       w1, b1, w2, b2, out);
    }
}

// Round 10
// 199.031 us; speedup vs baseline: 3.8630x; 1.0243x over previous
//
#include <hip/hip_runtime.h>

typedef unsigned int u32;
typedef unsigned short u16;
typedef _Float16 half_t;
typedef half_t h2   __attribute__((ext_vector_type(2)));
typedef half_t f16x8 __attribute__((ext_vector_type(8)));
typedef float  f32x4 __attribute__((ext_vector_type(4)));
typedef float  f32x2 __attribute__((ext_vector_type(2)));
typedef __fp16 fp16v2 __attribute__((ext_vector_type(2)));

#define NPTS 1048576

#if defined(__has_builtin)
#if __has_builtin(__builtin_amdgcn_cvt_pk_f32_fp8) && __has_builtin(__builtin_amdgcn_cvt_pk_fp8_f32) && __has_builtin(__builtin_amdgcn_cvt_pkrtz)
#define HAS_FP8 1
#endif
#endif
#ifndef HAS_FP8
#define HAS_FP8 0
#endif

// plain (unscaled) fp8->f16 pair convert — exact, no scale semantics to trust
#if HAS_FP8 && defined(__has_builtin)
#if __has_builtin(__builtin_amdgcn_cvt_pk_f16_fp8)
#define HAS_C16 1
#endif
#endif
#ifndef HAS_C16
#define HAS_C16 0
#endif

#if defined(__has_builtin)
#if __has_builtin(__builtin_amdgcn_update_dpp)
#define HAS_DPP 1
#endif
#endif
#ifndef HAS_DPP
#define HAS_DPP 0
#endif

// workspace dword layout (built by ga_prep from fp32 inputs)
#if HAS_FP8
#define WS_LINE_SZ  49056   // 3*511*32 dw: [c][i0][fpair fp8 tap-split: f0t0 f1t0 f0t1 f1t1]
#else
#define WS_LINE_SZ  98112   // 3*511*2*32 dw: [c][i0][tap][fpair] f16 (256 B/i0)
#endif
#define WS_VOL_DW   (WS_LINE_SZ)            // 125*32 = 4000 dw: [vox][fpair] f16
#define WS_PLANE_DW (WS_VOL_DW + 4000)      // 3*400*32 dw: [pp][row][swizzled chunk][fpair] f16
#define WS_PZX8_DW  (WS_PLANE_DW + 38400)   // 400*18 dw: [row][fp8 x64 + pad]
#if HAS_FP8
#define WS_TOTAL_DW (WS_PZX8_DW + 7200)
#else
#define WS_TOTAL_DW (WS_PZX8_DW)
#endif
#define WS_TOTAL_BYTES (WS_TOTAL_DW * 4)

// LDS layout (dwords): planes xy,yz at 0 (25600 dw); volume at 25600 (125 rows x 36 dw);
// pzx-fp8 at 30100 (400 rows x 18 dw). Total 37300 dw = 149,200 B -> 1 block/CU.
#define LDS_VOL_DW   25600
#define LDS_PZ8_DW   30100
#define LDS_TOTAL_DW 37300
#define VOLB         (LDS_VOL_DW*4)    // 102400
#define PZ8B         (LDS_PZ8_DW*4)    // 120400

__device__ __forceinline__ u32 pkh(float a, float b) {
    union { h2 h; u32 u; } r;
    r.h = (h2){(half_t)a, (half_t)b};
    return r.u;
}
__device__ __forceinline__ h2 bc(float w) {
    half_t h = (half_t)w;
    return (h2){h, h};
}
__device__ __forceinline__ h2 pkrtz(float a, float b) {
    union { fp16v2 f; h2 h; } r;
    r.f = __builtin_amdgcn_cvt_pkrtz(a, b);
    return r.h;
}
#if HAS_C16
// fp8 byte-pair (word selected by HI) -> f16 pair, exact
template<bool HI>
__device__ __forceinline__ h2 c8h(u32 s) {
    auto t = __builtin_amdgcn_cvt_pk_f16_fp8((int)s, HI);
    h2 r;
    __builtin_memcpy(&r, &t, 4);
    return r;
}
#endif
#if HAS_DPP
// butterfly add: v += lane-permuted v (all lanes end with row sum after 4 stages)
template<int CTRL>
__device__ __forceinline__ float dpp_bfly(float v) {
    int t = __builtin_amdgcn_update_dpp(0, __float_as_int(v), CTRL, 0xF, 0xF, false);
    return v + __int_as_float(t);
}
#endif

union U4 { uint4 v; u32 s[4]; };

// ---------------------------------------------------------------------------
// Prep: fp32 inputs -> fp8 line tables (tap-split) + f16 vol/plane + fp8 pzx.
// ---------------------------------------------------------------------------
__global__ __launch_bounds__(256) void ga_prep(
    const float* __restrict__ lx, const float* __restrict__ ly, const float* __restrict__ lz,
    const float* __restrict__ pxy, const float* __restrict__ pyz, const float* __restrict__ pzx,
    const float* __restrict__ vol, u32* __restrict__ ws)
{
    const int stride = gridDim.x * blockDim.x;
    for (int t = blockIdx.x * blockDim.x + threadIdx.x; t < WS_TOTAL_DW; t += stride) {
        if (t < WS_LINE_SZ) {
#if HAS_FP8
            // fp8 lines, tap-split: dw d of row i0 = bytes (f0t0, f1t0, f0t1, f1t1)
            const int c  = t / 16352;           // 511*32
            const int r  = t - c * 16352;
            const int i0 = r >> 5;              // 0..510
            const int d  = r & 31;
            const float* L = (c == 0) ? lx : (c == 1) ? ly : lz;
            const int f0 = 2*d, f1 = 2*d + 1;
            int v = 0;
            v = __builtin_amdgcn_cvt_pk_fp8_f32(L[f0*512 + i0],     L[f1*512 + i0],     v, false);
            v = __builtin_amdgcn_cvt_pk_fp8_f32(L[f0*512 + i0 + 1], L[f1*512 + i0 + 1], v, true);
            ws[t] = (u32)v;
#else
            const int c  = t / 32704;           // 511*64
            const int r  = t - c * 32704;
            const int i0 = r >> 6;
            const int w  = r & 63;
            const int tap = w >> 5;
            const int fp  = w & 31;
            const float* L = (c == 0) ? lx : (c == 1) ? ly : lz;
            ws[t] = pkh(L[(2*fp)*512 + i0 + tap], L[(2*fp+1)*512 + i0 + tap]);
#endif
        } else if (t < WS_PLANE_DW) {
            const int r = t - WS_VOL_DW;
            const int vox = r >> 5;
            const int fp  = r & 31;
            ws[t] = pkh(vol[(2*fp)*125 + vox], vol[(2*fp+1)*125 + vox]);
        } else if (t < WS_PZX8_DW) {
            const int r  = t - WS_PLANE_DW;
            const int pp = r / 12800;
            const int rr = r - pp * 12800;
            const int row = rr >> 5;            // 0..399 (= y*20+x)
            const int c   = rr & 31;            // fpair index
            const int chunk = c >> 2;
            const int ci    = c & 3;
            const int pos = ((chunk ^ (row & 7)) << 2) + ci;  // XOR swizzle
            const float* P = (pp == 0) ? pxy : (pp == 1) ? pyz : pzx;
            const int f = c * 2;
            ws[WS_PLANE_DW + pp*12800 + (row << 5) + pos] =
                pkh(P[f*400 + row], P[(f+1)*400 + row]);
        } else {
#if HAS_FP8
            const int t2 = t - WS_PZX8_DW;
            const int row = t2 / 18;
            const int d   = t2 - row * 18;
            u32 v = 0;
            if (d < 16) {
                const int f0 = d * 4;
                int dw = 0;
                dw = __builtin_amdgcn_cvt_pk_fp8_f32(pzx[(f0+0)*400+row], pzx[(f0+1)*400+row], dw, false);
                dw = __builtin_amdgcn_cvt_pk_fp8_f32(pzx[(f0+2)*400+row], pzx[(f0+3)*400+row], dw, true);
                v = (u32)dw;
            }
            ws[t] = v;
#endif
        }
    }
}

// ---------------------------------------------------------------------------
// Main: lane = (point p = lane&15, feature group fg = lane>>4).
// LDS: planes xy,yz (f16) + padded volume (f16) + pzx (fp8).
// Lines from L2 as fp8 (6.4 divergent lines/point).
// fp8 decode via plain v_cvt_pk_f16_fp8 (exact); layer-2 reduce via DPP.
// ---------------------------------------------------------------------------
__global__ __launch_bounds__(1024, 4) void ga_main(
    const float* __restrict__ coords,
    const float* __restrict__ w1,
    const float* __restrict__ b1,
    const float* __restrict__ w2,
    const float* __restrict__ b2,
    const u32* __restrict__ ws,
    float* __restrict__ out)
{
    __shared__ u32 sP[LDS_TOTAL_DW];   // 149,200 B
    const int tid = threadIdx.x;
    {
        const uint4* src = (const uint4*)(ws + WS_PLANE_DW);
        uint4* dst = (uint4*)sP;
        #pragma unroll
        for (int i = 0; i < 7; ++i) {
            int idx = tid + i * 1024;
            if (idx < 6400) dst[idx] = src[idx];
        }
        if (tid < 1000) {
            const int vox = tid >> 3, ch = tid & 7;
            ((uint4*)(sP + LDS_VOL_DW))[vox*9 + ch] = ((const uint4*)(ws + WS_VOL_DW))[tid];
        }
#if HAS_FP8
        #pragma unroll
        for (int i = 0; i < 2; ++i) {
            int idx = tid + i * 1024;
            if (idx < 1800)
                ((uint4*)(sP + LDS_PZ8_DW))[idx] = ((const uint4*)(ws + WS_PZX8_DW))[idx];
        }
#endif
    }
    __syncthreads();

    const int lane = tid & 63;
    const int wave = tid >> 6;       // 0..15
    const int p    = lane & 15;
    const int fg   = lane >> 4;      // 0..3
    const int wgbase = blockIdx.x << 12;   // 4096 points per workgroup

    // w1 B-fragments (f16)
    f16x8 wfrag[4][2];
    #pragma unroll
    for (int t = 0; t < 4; ++t) {
        #pragma unroll
        for (int h = 0; h < 2; ++h) {
            const float* src = w1 + ((16*t + p)*64 + h*32 + fg*8);
            f16x8 w;
            #pragma unroll
            for (int e = 0; e < 8; ++e) w[e] = (half_t)src[e];
            wfrag[t][h] = w;
        }
    }
    float b1v[4], w2v[4];
    #pragma unroll
    for (int t = 0; t < 4; ++t) { b1v[t] = b1[16*t + p]; w2v[t] = w2[16*t + p]; }
    const float b2v = b2[0];

    const char* wsb = (const char*)ws;
    const char* spb = (const char*)sP;

    // coords prefetch (software pipeline, depth 1)
    float cx = coords[3*(wgbase + (wave<<4) + p) + 0];
    float cy = coords[3*(wgbase + (wave<<4) + p) + 1];
    float cz = coords[3*(wgbase + (wave<<4) + p) + 2];

    for (int g = wave; g < 256; g += 16) {
        const int pbase = wgbase + (g << 4);
        const int gn = (g + 16 < 256) ? g + 16 : g;
        const int ptn = wgbase + (gn << 4) + p;
        const float nx = coords[3*ptn + 0];
        const float ny = coords[3*ptn + 1];
        const float nz = coords[3*ptn + 2];

        int lidx[3], pidx[3], vidx[3];
        float lww[3], lwm[3], pww[3], pwm[3], vww[3], vwm[3];
        {
            const float uu[3] = { (cx+1.f)*0.5f, (cy+1.f)*0.5f, (cz+1.f)*0.5f };
            #pragma unroll
            for (int c = 0; c < 3; ++c) {
                float pos = fminf(fmaxf(uu[c]*511.f, 0.f), 511.f);
                float i0 = fminf(floorf(pos), 510.f);
                lidx[c] = (int)i0; lww[c] = pos - i0; lwm[c] = 1.f - lww[c];
                float pq = fminf(fmaxf(uu[c]*19.f, 0.f), 19.f);
                float pi0 = fminf(floorf(pq), 18.f);
                pidx[c] = (int)pi0; pww[c] = pq - pi0; pwm[c] = 1.f - pww[c];
                float vq = fminf(fmaxf(uu[c]*4.f, 0.f), 4.f);
                float vi0 = fminf(floorf(vq), 3.f);
                vidx[c] = (int)vi0; vww[c] = vq - vi0; vwm[c] = 1.f - vww[c];
            }
        }
        // line byte bases
        int laddr[3];
        #pragma unroll
        for (int c = 0; c < 3; ++c)
#if HAS_FP8
            laddr[c] = (c*511 + lidx[c])*128 + fg*16;   // fp8: 128 B/i0, cc chunk at +64
#else
            laddr[c] = (c*511 + lidx[c])*256 + fg*16;   // f16: 256 B/i0, tap1 +128, cc +64
#endif
        // planes xy,yz: corner weights + swizzled LDS addresses
        float wqf[2][4];
        int paddr[2][4];
        #pragma unroll
        for (int pp = 0; pp < 2; ++pp) {
            const int a = (pp==0)?0:1;    // gx axis (col)
            const int b = (pp==0)?1:2;    // gy axis (row)
            wqf[pp][0] = pwm[b]*pwm[a]; wqf[pp][1] = pwm[b]*pww[a];
            wqf[pp][2] = pww[b]*pwm[a]; wqf[pp][3] = pww[b]*pww[a];
            const int r00 = pidx[b]*20 + pidx[a];
            const int roff[4] = {0, 1, 20, 21};
            #pragma unroll
            for (int k = 0; k < 4; ++k) {
                const int r = r00 + roff[k];
                paddr[pp][k] = pp*51200 + r*128 + ((fg ^ (r & 7)) << 4);
            }
        }
        // plane zx: gx=z (col), gy=x (row)
        int prow[4];
        h2 wq2b[4];
        {
            wq2b[0] = bc(pwm[0]*pwm[2]); wq2b[1] = bc(pwm[0]*pww[2]);
            wq2b[2] = bc(pww[0]*pwm[2]); wq2b[3] = bc(pww[0]*pww[2]);
            const int r00 = pidx[0]*20 + pidx[2];
            const int roff[4] = {0, 1, 20, 21};
            #pragma unroll
            for (int k = 0; k < 4; ++k) {
#if HAS_FP8
                prow[k] = PZ8B + (r00 + roff[k])*72;
#else
                const int r = r00 + roff[k];
                prow[k] = WS_PLANE_DW*4 + 2*51200 + r*128 + ((fg ^ (r & 7)) << 4);
#endif
            }
        }
        // volume: LDS, padded rows (144 B)
        const int vox00 = (vidx[2]*5 + vidx[1])*5 + vidx[0];
        const int vb = VOLB + vox00*144 + fg*16;
        float wvf[8];
        #pragma unroll
        for (int dz = 0; dz < 2; ++dz)
            #pragma unroll
            for (int dy = 0; dy < 2; ++dy)
                #pragma unroll
                for (int dx = 0; dx < 2; ++dx)
                    wvf[dz*4+dy*2+dx] = (dz?vww[2]:vwm[2])*(dy?vww[1]:vwm[1])*(dx?vww[0]:vwm[0]);

        // h2 weight broadcasts
        h2 wqb[2][4], wvb[8];
        #pragma unroll
        for (int pp = 0; pp < 2; ++pp)
            #pragma unroll
            for (int k = 0; k < 4; ++k) wqb[pp][k] = bc(wqf[pp][k]);
        #pragma unroll
        for (int t = 0; t < 8; ++t) wvb[t] = bc(wvf[t]);
#if HAS_C16 || !HAS_FP8
        h2 wlm2[3], wlw2[3];
        #pragma unroll
        for (int c = 0; c < 3; ++c) { wlm2[c] = bc(lwm[c]); wlw2[c] = bc(lww[c]); }
#endif

        union UH { uint4 v; h2 h[4]; };
        h2 comb[2][4];
        #pragma unroll
        for (int cc = 0; cc < 2; ++cc) {
            const int co = cc * 64;
            // ---- global loads first: lines (3 b128 fp8 / 6 b128 f16) ----
#if HAS_FP8
            U4 LX, LY, LZ;
            LX.v = *(const uint4*)(wsb + laddr[0] + co);
            LY.v = *(const uint4*)(wsb + laddr[1] + co);
            LZ.v = *(const uint4*)(wsb + laddr[2] + co);
#else
            UH X0, X1, Y0, Y1, Z0, Z1;
            X0.v = *(const uint4*)(wsb + laddr[0] + co);
            X1.v = *(const uint4*)(wsb + laddr[0] + co + 128);
            Y0.v = *(const uint4*)(wsb + laddr[1] + co);
            Y1.v = *(const uint4*)(wsb + laddr[1] + co + 128);
            Z0.v = *(const uint4*)(wsb + laddr[2] + co);
            Z1.v = *(const uint4*)(wsb + laddr[2] + co + 128);
#endif
            // ---- volume from LDS while globals fly ----
            UH V[8];
            #pragma unroll
            for (int dz = 0; dz < 2; ++dz)
                #pragma unroll
                for (int dy = 0; dy < 2; ++dy)
                    #pragma unroll
                    for (int dx = 0; dx < 2; ++dx)
                        V[dz*4+dy*2+dx].v =
                            *(const uint4*)(spb + vb + (dz*25+dy*5+dx)*144 + co);
            #pragma unroll
            for (int j = 0; j < 4; ++j) {
                h2 s = V[0].h[j]*wvb[0] + V[1].h[j]*wvb[1]
                     + V[2].h[j]*wvb[2] + V[3].h[j]*wvb[3];
                s += V[4].h[j]*wvb[4] + V[5].h[j]*wvb[5]
                   + V[6].h[j]*wvb[6] + V[7].h[j]*wvb[7];
                comb[cc][j] = s;
            }
            // ---- plane zx: fp8 from LDS ----
            h2 pa2[4];
            #pragma unroll
            for (int j = 0; j < 4; ++j) pa2[j] = (h2){(half_t)0.f, (half_t)0.f};
#if HAS_C16
            #pragma unroll
            for (int k = 0; k < 4; ++k) {
                const uint2 q = *(const uint2*)(spb + prow[k] + cc*32 + fg*8);
                pa2[0] += c8h<false>(q.x) * wq2b[k];
                pa2[1] += c8h<true >(q.x) * wq2b[k];
                pa2[2] += c8h<false>(q.y) * wq2b[k];
                pa2[3] += c8h<true >(q.y) * wq2b[k];
            }
#elif HAS_FP8
            #pragma unroll
            for (int k = 0; k < 4; ++k) {
                const uint2 q = *(const uint2*)(spb + prow[k] + cc*32 + fg*8);
                f32x2 e0 = __builtin_amdgcn_cvt_pk_f32_fp8((int)q.x, false);
                f32x2 e1 = __builtin_amdgcn_cvt_pk_f32_fp8((int)q.x, true);
                f32x2 e2 = __builtin_amdgcn_cvt_pk_f32_fp8((int)q.y, false);
                f32x2 e3 = __builtin_amdgcn_cvt_pk_f32_fp8((int)q.y, true);
                h2 ha = pkrtz(e0.x, e0.y);
                h2 hb = pkrtz(e1.x, e1.y);
                h2 hc = pkrtz(e2.x, e2.y);
                h2 hd = pkrtz(e3.x, e3.y);
                pa2[0] += ha*wq2b[0*0+k]; pa2[1] += hb*wq2b[k];
                pa2[2] += hc*wq2b[k];     pa2[3] += hd*wq2b[k];
            }
#else
            {
                UH q0, q1, q2, q3;
                q0.v = *(const uint4*)(wsb + (prow[0] ^ co));
                q1.v = *(const uint4*)(wsb + (prow[1] ^ co));
                q2.v = *(const uint4*)(wsb + (prow[2] ^ co));
                q3.v = *(const uint4*)(wsb + (prow[3] ^ co));
                #pragma unroll
                for (int j = 0; j < 4; ++j)
                    pa2[j] = q0.h[j]*wq2b[0] + q1.h[j]*wq2b[1]
                           + q2.h[j]*wq2b[2] + q3.h[j]*wq2b[3];
            }
#endif
            // ---- line lerps ----
            h2 fx[4], fy[4], fz[4];
#if HAS_C16
            #pragma unroll
            for (int i = 0; i < 4; ++i) {
                // lo = (f0t0,f1t0), hi = (f0t1,f1t1): lerp entirely in packed f16
                fx[i] = c8h<false>(LX.s[i])*wlm2[0] + c8h<true>(LX.s[i])*wlw2[0];
                fy[i] = c8h<false>(LY.s[i])*wlm2[1] + c8h<true>(LY.s[i])*wlw2[1];
                fz[i] = c8h<false>(LZ.s[i])*wlm2[2] + c8h<true>(LZ.s[i])*wlw2[2];
            }
#elif HAS_FP8
            #pragma unroll
            for (int i = 0; i < 4; ++i) {
                f32x2 xa = __builtin_amdgcn_cvt_pk_f32_fp8((int)LX.s[i], false);  // (f0t0,f1t0)
                f32x2 xb = __builtin_amdgcn_cvt_pk_f32_fp8((int)LX.s[i], true);   // (f0t1,f1t1)
                fx[i] = pkrtz(xa.x*lwm[0] + xb.x*lww[0], xa.y*lwm[0] + xb.y*lww[0]);
                f32x2 ya = __builtin_amdgcn_cvt_pk_f32_fp8((int)LY.s[i], false);
                f32x2 yb = __builtin_amdgcn_cvt_pk_f32_fp8((int)LY.s[i], true);
                fy[i] = pkrtz(ya.x*lwm[1] + yb.x*lww[1], ya.y*lwm[1] + yb.y*lww[1]);
                f32x2 za = __builtin_amdgcn_cvt_pk_f32_fp8((int)LZ.s[i], false);
                f32x2 zb = __builtin_amdgcn_cvt_pk_f32_fp8((int)LZ.s[i], true);
                fz[i] = pkrtz(za.x*lwm[2] + zb.x*lww[2], za.y*lwm[2] + zb.y*lww[2]);
            }
#else
            #pragma unroll
            for (int j = 0; j < 4; ++j) {
                fx[j] = X0.h[j]*wlm2[0] + X1.h[j]*wlw2[0];
                fy[j] = Y0.h[j]*wlm2[1] + Y1.h[j]*wlw2[1];
                fz[j] = Z0.h[j]*wlm2[2] + Z1.h[j]*wlw2[2];
            }
#endif
            #pragma unroll
            for (int j = 0; j < 4; ++j) comb[cc][j] += fx[j]*fy[j]*fz[j];
            // ---- planes xy,yz from LDS ----
            #pragma unroll
            for (int pp = 0; pp < 2; ++pp) {
                UH r0, r1, r2, r3;
                r0.v = *(const uint4*)(spb + (paddr[pp][0] ^ co));
                r1.v = *(const uint4*)(spb + (paddr[pp][1] ^ co));
                r2.v = *(const uint4*)(spb + (paddr[pp][2] ^ co));
                r3.v = *(const uint4*)(spb + (paddr[pp][3] ^ co));
                #pragma unroll
                for (int j = 0; j < 4; ++j) {
                    h2 pa = r0.h[j]*wqb[pp][0] + r1.h[j]*wqb[pp][1]
                          + r2.h[j]*wqb[pp][2] + r3.h[j]*wqb[pp][3];
                    const h2 lf = (pp==0) ? fz[j] : fx[j];
                    comb[cc][j] += pa * lf;
                }
            }
            // ---- plane zx contribution ----
            #pragma unroll
            for (int j = 0; j < 4; ++j) comb[cc][j] += pa2[j] * fy[j];
        }
        // MLP layer 1 via f16 MFMA; comb is already the A-fragment
        union AF { f16x8 v; h2 h[4]; } A0, A1;
        #pragma unroll
        for (int j = 0; j < 4; ++j) { A0.h[j] = comb[0][j]; A1.h[j] = comb[1][j]; }
        f32x4 acc0 = {0.f,0.f,0.f,0.f};
        f32x4 acc1 = {0.f,0.f,0.f,0.f};
        f32x4 acc2 = {0.f,0.f,0.f,0.f};
        f32x4 acc3 = {0.f,0.f,0.f,0.f};
        acc0 = __builtin_amdgcn_mfma_f32_16x16x32_f16(A0.v, wfrag[0][0], acc0, 0, 0, 0);
        acc0 = __builtin_amdgcn_mfma_f32_16x16x32_f16(A1.v, wfrag[0][1], acc0, 0, 0, 0);
        acc1 = __builtin_amdgcn_mfma_f32_16x16x32_f16(A0.v, wfrag[1][0], acc1, 0, 0, 0);
        acc1 = __builtin_amdgcn_mfma_f32_16x16x32_f16(A1.v, wfrag[1][1], acc1, 0, 0, 0);
        acc2 = __builtin_amdgcn_mfma_f32_16x16x32_f16(A0.v, wfrag[2][0], acc2, 0, 0, 0);
        acc2 = __builtin_amdgcn_mfma_f32_16x16x32_f16(A1.v, wfrag[2][1], acc2, 0, 0, 0);
        acc3 = __builtin_amdgcn_mfma_f32_16x16x32_f16(A0.v, wfrag[3][0], acc3, 0, 0, 0);
        acc3 = __builtin_amdgcn_mfma_f32_16x16x32_f16(A1.v, wfrag[3][1], acc3, 0, 0, 0);
        // layer 2: relu + dot with w2; reduce across the 16 C-layout columns
        float sr[4];
        #pragma unroll
        for (int r = 0; r < 4; ++r) {
            float s = fmaxf(acc0[r] + b1v[0], 0.f) * w2v[0];
            s = fmaf(fmaxf(acc1[r] + b1v[1], 0.f), w2v[1], s);
            s = fmaf(fmaxf(acc2[r] + b1v[2], 0.f), w2v[2], s);
            s = fmaf(fmaxf(acc3[r] + b1v[3], 0.f), w2v[3], s);
            sr[r] = s;
        }
#if HAS_DPP
        // butterfly within each 16-lane row: quad xor1, quad xor2, half-mirror, mirror
        #pragma unroll
        for (int r = 0; r < 4; ++r) {
            float s = sr[r];
            s = dpp_bfly<0xB1>(s);    // quad_perm [1,0,3,2]  (xor 1)
            s = dpp_bfly<0x4E>(s);    // quad_perm [2,3,0,1]  (xor 2)
            s = dpp_bfly<0x141>(s);   // row_half_mirror      (xor 7 within 8)
            s = dpp_bfly<0x140>(s);   // row_mirror           (xor 15 within 16)
            sr[r] = s;
        }
#else
        #pragma unroll
        for (int m = 1; m <= 8; m <<= 1) {
            #pragma unroll
            for (int r = 0; r < 4; ++r) sr[r] += __shfl_xor(sr[r], m, 64);
        }
#endif
        if (p == 0) {
            float4 o;
            o.x = sr[0] + b2v;
            o.y = sr[1] + b2v;
            o.z = sr[2] + b2v;
            o.w = sr[3] + b2v;
            *(float4*)(out + pbase + (fg << 2)) = o;
        }
        cx = nx; cy = ny; cz = nz;
    }
}

// ---------------------------------------------------------------------------
// Fallback (only if ws_size is too small): slow but correct, thread-per-point.
// ---------------------------------------------------------------------------
__global__ __launch_bounds__(256) void ga_naive(
    const float* __restrict__ coords,
    const float* __restrict__ lx, const float* __restrict__ ly, const float* __restrict__ lz,
    const float* __restrict__ pxy, const float* __restrict__ pyz, const float* __restrict__ pzx,
    const float* __restrict__ vol,
    const float* __restrict__ w1, const float* __restrict__ b1,
    const float* __restrict__ w2, const float* __restrict__ b2,
    float* __restrict__ out)
{
    const int n = blockIdx.x * blockDim.x + threadIdx.x;
    if (n >= NPTS) return;
    int lidx[3], pidx[3], vidx[3];
    float lww[3], lwm[3], pww[3], pwm[3], vww[3], vwm[3];
    for (int c = 0; c < 3; ++c) {
        const float cv = coords[3*n + c];
        const float u = (cv + 1.f)*0.5f;
        float pos = fminf(fmaxf(u*511.f, 0.f), 511.f);
        float i0 = fminf(floorf(pos), 510.f);
        lidx[c] = (int)i0; lww[c] = pos - i0; lwm[c] = 1.f - lww[c];
        float pq = fminf(fmaxf(u*19.f, 0.f), 19.f);
        float pi0 = fminf(floorf(pq), 18.f);
        pidx[c] = (int)pi0; pww[c] = pq - pi0; pwm[c] = 1.f - pww[c];
        float vq = fminf(fmaxf(u*4.f, 0.f), 4.f);
        float vi0 = fminf(floorf(vq), 3.f);
        vidx[c] = (int)vi0; vww[c] = vq - vi0; vwm[c] = 1.f - vww[c];
    }
    float comb[64];
    for (int f = 0; f < 64; ++f) {
        const float fxv = lwm[0]*lx[f*512+lidx[0]] + lww[0]*lx[f*512+lidx[0]+1];
        const float fyv = lwm[1]*ly[f*512+lidx[1]] + lww[1]*ly[f*512+lidx[1]+1];
        const float fzv = lwm[2]*lz[f*512+lidx[2]] + lww[2]*lz[f*512+lidx[2]+1];
        const int bxy = f*400 + pidx[1]*20 + pidx[0];
        const float pxyv = pwm[1]*pwm[0]*pxy[bxy]    + pwm[1]*pww[0]*pxy[bxy+1]
                         + pww[1]*pwm[0]*pxy[bxy+20] + pww[1]*pww[0]*pxy[bxy+21];
        const int byz = f*400 + pidx[2]*20 + pidx[1];
        const float pyzv = pwm[2]*pwm[1]*pyz[byz]    + pwm[2]*pww[1]*pyz[byz+1]
                         + pww[2]*pwm[1]*pyz[byz+20] + pww[2]*pww[1]*pyz[byz+21];
        const int bzx = f*400 + pidx[0]*20 + pidx[2];
        const float pzxv = pwm[0]*pwm[2]*pzx[bzx]    + pwm[0]*pww[2]*pzx[bzx+1]
                         + pww[0]*pwm[2]*pzx[bzx+20] + pww[0]*pww[2]*pzx[bzx+21];
        const int bv = f*125 + (vidx[2]*5 + vidx[1])*5 + vidx[0];
        float vv = 0.f;
        for (int dz = 0; dz < 2; ++dz)
            for (int dy = 0; dy < 2; ++dy)
                for (int dx = 0; dx < 2; ++dx) {
                    const float w = (dz ? vww[2] : vwm[2]) * (dy ? vww[1] : vwm[1]) * (dx ? vww[0] : vwm[0]);
                    vv += w * vol[bv + dz*25 + dy*5 + dx];
                }
        comb[f] = fxv*fyv*fzv + pxyv*fzv + pyzv*fxv + pzxv*fyv + vv;
    }
    float o = b2[0];
    for (int gg = 0; gg < 64; ++gg) {
        float h = b1[gg];
        for (int f = 0; f < 64; ++f) h = fmaf(comb[f], w1[gg*64 + f], h);
        o = fmaf(fmaxf(h, 0.f), w2[gg], o);
    }
    out[n] = o;
}

extern "C" void kernel_launch(void* const* d_in, const int* in_sizes, int n_in,
                              void* d_out, int out_size, void* d_ws, size_t ws_size,
                              hipStream_t stream)
{
    const float* coords = (const float*)d_in[0];
    const float* lx  = (const float*)d_in[1];
    const float* ly  = (const float*)d_in[2];
    const float* lz  = (const float*)d_in[3];
    const float* pxy = (const float*)d_in[4];
    const float* pyz = (const float*)d_in[5];
    const float* pzx = (const float*)d_in[6];
    const float* vol = (const float*)d_in[7];
    const float* w1  = (const float*)d_in[8];
    const float* b1  = (const float*)d_in[9];
    const float* w2  = (const float*)d_in[10];
    const float* b2  = (const float*)d_in[11];
    float* out = (float*)d_out;
    if (ws_size >= (size_t)WS_TOTAL_BYTES) {
        u32* ws = (u32*)d_ws;
        ga_prep<<<dim3(400), dim3(256), 0, stream>>>(lx, ly, lz, pxy, pyz, pzx, vol, ws);
        ga_main<<<dim3(256), dim3(1024), 0, stream>>>(coords, w1, b1, w2, b2, ws, out);
    } else {
        ga_naive<<<dim3(4096), dim3(256), 0, stream>>>(coords, lx, ly, lz, pxy, pyz, pzx, vol,
                                                       w1, b1, w2, b2, out);
    }
}